// Round 1
// baseline (26042.615 us; speedup 1.0000x reference)
//
#include <hip/hip_runtime.h>
#include <math.h>

#define DEV_INLINE __device__ __forceinline__

constexpr int BB     = 32;
constexpr int DMODEL = 768;
constexpr int NHEAD  = 12;
constexpr int NPATCH = 196;
constexpr int NTOK   = 197;    // max tokens (196 patches + CLS)
constexpr int NLAYER = 12;
constexpr int NCLASS = 1000;
constexpr int MTOT   = BB * NTOK;   // 6304

// ---------------------------------------------------------------- reductions
DEV_INLINE float block_reduce_sum(float v, float* sbuf) {
    #pragma unroll
    for (int off = 32; off > 0; off >>= 1) v += __shfl_down(v, off, 64);
    int lane = threadIdx.x & 63, w = threadIdx.x >> 6;
    __syncthreads();                       // protect sbuf reuse across calls
    if (lane == 0) sbuf[w] = v;
    __syncthreads();
    return sbuf[0] + sbuf[1] + sbuf[2] + sbuf[3];
}

// ---------------------------------------------------------------- state init
__global__ void state_init(int* nTokPtr, int* prevValidPtr) {
    *nTokPtr = NTOK;
    *prevValidPtr = 0;
}

// ------------------------------------------------------- patch_w transpose
// wT[k][d] = patch_w[d][k], 768x768
__global__ __launch_bounds__(256)
void transpose768(const float* __restrict__ src, float* __restrict__ dst) {
    __shared__ float tile[32][33];
    int bx = blockIdx.x * 32;   // k block
    int by = blockIdx.y * 32;   // d block
    int tx = threadIdx.x, ty = threadIdx.y;   // 32 x 8
    #pragma unroll
    for (int i = 0; i < 32; i += 8)
        tile[ty + i][tx] = src[(size_t)(by + ty + i) * 768 + bx + tx];
    __syncthreads();
    #pragma unroll
    for (int i = 0; i < 32; i += 8)
        dst[(size_t)(bx + ty + i) * 768 + by + tx] = tile[tx][ty + i];
}

// ---------------------------------------------------------------- CLS row
__global__ __launch_bounds__(256)
void cls_init(const float* __restrict__ cls, const float* __restrict__ pos,
              float* __restrict__ tok) {
    int b = blockIdx.x;
    for (int i = threadIdx.x; i < DMODEL; i += 256)
        tok[(size_t)b * NTOK * DMODEL + i] = cls[i] + pos[i];
}

// ------------------------------------------------------------ patch-embed GEMM
// im2col(x) [6272 x 768] @ wT [768 x 768] -> tok rows 1..196 (+bias +pos)
__global__ __launch_bounds__(256)
void gemm_patch(const float* __restrict__ x, const float* __restrict__ wT,
                const float* __restrict__ pbias, const float* __restrict__ pos,
                float* __restrict__ tok) {
    const int m0 = blockIdx.x * 128;
    const int n0 = blockIdx.y * 128;
    __shared__ float As[16][132];
    __shared__ float Bs[16][132];
    const int tid = threadIdx.x;
    const int tx = tid & 15, ty = tid >> 4;
    const int a_c = tid & 15, a_r0 = tid >> 4;
    const int b_j = tid & 127, b_c0 = tid >> 7;
    size_t abase[8];
    #pragma unroll
    for (int rr = 0; rr < 8; rr++) {
        int m = m0 + a_r0 + rr * 16;
        int b = m / NPATCH;
        int p = m - b * NPATCH;
        int py = p / 14, px = p - py * 14;
        abase[rr] = (size_t)b * 3 * 224 * 224 + (size_t)(py * 16) * 224 + px * 16;
    }
    float acc[8][8] = {};
    for (int k0 = 0; k0 < 768; k0 += 16) {
        int k = k0 + a_c;
        int c = k >> 8, rem = k & 255, ii = rem >> 4, jj = rem & 15;
        size_t koff = ((size_t)c * 224 + ii) * 224 + jj;
        #pragma unroll
        for (int rr = 0; rr < 8; rr++)
            As[a_c][a_r0 + rr * 16] = x[abase[rr] + koff];
        #pragma unroll
        for (int cc = 0; cc < 8; cc++) {
            int ck = b_c0 + cc * 2;
            Bs[ck][b_j] = wT[(size_t)(k0 + ck) * 768 + n0 + b_j];
        }
        __syncthreads();
        #pragma unroll
        for (int kk = 0; kk < 16; kk++) {
            float ra[8], rb[8];
            #pragma unroll
            for (int i = 0; i < 8; i++) ra[i] = As[kk][ty * 8 + i];
            #pragma unroll
            for (int j = 0; j < 8; j++) rb[j] = Bs[kk][tx * 8 + j];
            #pragma unroll
            for (int i = 0; i < 8; i++)
                #pragma unroll
                for (int j = 0; j < 8; j++)
                    acc[i][j] = fmaf(ra[i], rb[j], acc[i][j]);
        }
        __syncthreads();
    }
    #pragma unroll
    for (int i = 0; i < 8; i++) {
        int m = m0 + ty * 8 + i;
        int b = m / NPATCH, p = m - b * NPATCH;
        #pragma unroll
        for (int j = 0; j < 8; j++) {
            int n = n0 + tx * 8 + j;
            tok[((size_t)b * NTOK + 1 + p) * DMODEL + n] =
                acc[i][j] + pbias[n] + pos[(size_t)(1 + p) * DMODEL + n];
        }
    }
}

// ------------------------------------------------------------- token GEMM
// C[m,n] = sum_k A[m,k] * W[k,n] + bias[n]  (EPI1: +resid, EPI2: exact GELU)
// rows masked by (m % 197) < nTok
template<int EPI>
__global__ __launch_bounds__(256)
void gemm_tok(const float* __restrict__ A, int lda,
              const float* __restrict__ W, int ldb,
              const float* __restrict__ bias,
              const float* __restrict__ resid,
              float* __restrict__ C, int ldc,
              int K, int Mtot, const int* __restrict__ nTokPtr) {
    const int nTok = *nTokPtr;
    const int m0 = blockIdx.x * 128;
    const int n0 = blockIdx.y * 128;
    if (m0 >= Mtot) return;
    {
        int tstart = m0 % NTOK;
        if (!(tstart < nTok || tstart + 128 > NTOK)) return;   // whole tile invalid
    }
    __shared__ float As[16][132];
    __shared__ float Bs[16][132];
    const int tid = threadIdx.x;
    const int tx = tid & 15, ty = tid >> 4;
    const int a_c = tid & 15, a_r0 = tid >> 4;
    const int b_j = tid & 127, b_c0 = tid >> 7;
    int arow[8]; bool aval[8];
    #pragma unroll
    for (int rr = 0; rr < 8; rr++) {
        int m = m0 + a_r0 + rr * 16;
        arow[rr] = m;
        aval[rr] = (m < Mtot) && ((m % NTOK) < nTok);
    }
    float acc[8][8] = {};
    for (int k0 = 0; k0 < K; k0 += 16) {
        #pragma unroll
        for (int rr = 0; rr < 8; rr++) {
            float v = 0.f;
            if (aval[rr]) v = A[(size_t)arow[rr] * lda + k0 + a_c];
            As[a_c][a_r0 + rr * 16] = v;
        }
        #pragma unroll
        for (int cc = 0; cc < 8; cc++) {
            int c = b_c0 + cc * 2;
            Bs[c][b_j] = W[(size_t)(k0 + c) * ldb + n0 + b_j];
        }
        __syncthreads();
        #pragma unroll
        for (int kk = 0; kk < 16; kk++) {
            float ra[8], rb[8];
            #pragma unroll
            for (int i = 0; i < 8; i++) ra[i] = As[kk][ty * 8 + i];
            #pragma unroll
            for (int j = 0; j < 8; j++) rb[j] = Bs[kk][tx * 8 + j];
            #pragma unroll
            for (int i = 0; i < 8; i++)
                #pragma unroll
                for (int j = 0; j < 8; j++)
                    acc[i][j] = fmaf(ra[i], rb[j], acc[i][j]);
        }
        __syncthreads();
    }
    #pragma unroll
    for (int i = 0; i < 8; i++) {
        int m = m0 + ty * 8 + i;
        if (m >= Mtot) continue;
        if ((m % NTOK) >= nTok) continue;
        #pragma unroll
        for (int j = 0; j < 8; j++) {
            int n = n0 + tx * 8 + j;
            float v = acc[i][j] + bias[n];
            if constexpr (EPI == 1) v += resid[(size_t)m * ldc + n];
            if constexpr (EPI == 2) v = 0.5f * v * (1.0f + erff(v * 0.70710678118654752f));
            C[(size_t)m * ldc + n] = v;
        }
    }
}

// ---------------------------------------------------------------- LayerNorm
DEV_INLINE void ln_row(const float* __restrict__ x, float* __restrict__ y,
                       const float* __restrict__ w, const float* __restrict__ b,
                       float* sbuf) {
    int tid = threadIdx.x;
    float v[3];
    #pragma unroll
    for (int i = 0; i < 3; i++) v[i] = x[tid + i * 256];
    float mu = block_reduce_sum(v[0] + v[1] + v[2], sbuf) * (1.0f / 768.0f);
    float d2 = 0.f;
    #pragma unroll
    for (int i = 0; i < 3; i++) { float d = v[i] - mu; d2 = fmaf(d, d, d2); }
    float var = block_reduce_sum(d2, sbuf) * (1.0f / 768.0f);
    float rstd = rsqrtf(var + 1e-6f);
    #pragma unroll
    for (int i = 0; i < 3; i++) {
        int idx = tid + i * 256;
        y[idx] = (v[i] - mu) * rstd * w[idx] + b[idx];
    }
}

__global__ __launch_bounds__(256)
void ln_tok(const float* __restrict__ X, float* __restrict__ Y,
            const float* __restrict__ w, const float* __restrict__ b,
            const int* __restrict__ nTokPtr) {
    int m = blockIdx.x;
    if ((m % NTOK) >= *nTokPtr) return;
    __shared__ float sbuf[4];
    ln_row(X + (size_t)m * DMODEL, Y + (size_t)m * DMODEL, w, b, sbuf);
}

__global__ __launch_bounds__(256)
void ln_cls(const float* __restrict__ X, float* __restrict__ Y,
            const float* __restrict__ w, const float* __restrict__ b) {
    int bb = blockIdx.x;
    __shared__ float sbuf[4];
    ln_row(X + (size_t)bb * NTOK * DMODEL, Y + (size_t)bb * DMODEL, w, b, sbuf);
}

// ---------------------------------------------------------------- attention
// one block per (b,h); K in padded LDS, V read from global (coalesced)
__global__ __launch_bounds__(256)
void attn_kernel(const float* __restrict__ qkv, float* __restrict__ attnout,
                 float* __restrict__ jac, const int* __restrict__ nTokPtr) {
    const int nTok = *nTokPtr;
    const int bh = blockIdx.x;
    const int b = bh / NHEAD, h = bh % NHEAD;
    __shared__ float Ks[NTOK][65];
    __shared__ float vn[NTOK];
    __shared__ float qs[4][64];
    __shared__ float ps[4][NTOK];
    const int tid = threadIdx.x;
    const int lane = tid & 63, wv = tid >> 6;
    const float* base = qkv + (size_t)b * NTOK * 2304 + (size_t)h * 64;

    for (int t = wv; t < nTok; t += 4)
        Ks[t][lane] = base[(size_t)t * 2304 + 768 + lane];
    __syncthreads();
    for (int t = tid; t < nTok; t += 256) {
        const float* vrow = base + (size_t)t * 2304 + 1536;
        float s = 0.f;
        #pragma unroll
        for (int d = 0; d < 64; d++) s = fmaf(vrow[d], vrow[d], s);
        vn[t] = sqrtf(s);
    }
    __syncthreads();

    const float scale = 0.125f;   // 64^-0.5
    for (int q0 = 0; q0 < nTok; q0 += 4) {
        int q = q0 + wv;
        bool act = q < nTok;
        if (act) qs[wv][lane] = base[(size_t)q * 2304 + lane];
        __syncthreads();
        if (act) {
            float s[4];
            #pragma unroll
            for (int r = 0; r < 4; r++) {
                int j = lane + r * 64;
                if (j < nTok) {
                    float a = 0.f;
                    #pragma unroll
                    for (int d = 0; d < 64; d++) a = fmaf(qs[wv][d], Ks[j][d], a);
                    s[r] = a * scale;
                } else s[r] = -INFINITY;
            }
            float mx = fmaxf(fmaxf(s[0], s[1]), fmaxf(s[2], s[3]));
            #pragma unroll
            for (int off = 32; off > 0; off >>= 1) mx = fmaxf(mx, __shfl_xor(mx, off, 64));
            float e[4]; float sum = 0.f;
            #pragma unroll
            for (int r = 0; r < 4; r++) {
                int j = lane + r * 64;
                e[r] = (j < nTok) ? expf(s[r] - mx) : 0.f;
                sum += e[r];
            }
            #pragma unroll
            for (int off = 32; off > 0; off >>= 1) sum += __shfl_xor(sum, off, 64);
            float inv = 1.0f / sum;
            #pragma unroll
            for (int r = 0; r < 4; r++) {
                int j = lane + r * 64;
                if (j < nTok) {
                    float p = e[r] * inv;
                    ps[wv][j] = p;
                    if (q == 0 && j >= 1)
                        jac[((size_t)b * NHEAD + h) * NPATCH + (j - 1)] = p * vn[j];
                }
            }
            float acc = 0.f;
            const float* vbase = base + 1536 + lane;
            for (int j = 0; j < nTok; j++)
                acc = fmaf(ps[wv][j], vbase[(size_t)j * 2304], acc);
            attnout[((size_t)b * NTOK + q) * DMODEL + (size_t)h * 64 + lane] = acc;
        }
        __syncthreads();
    }
}

// ------------------------------------------------------- prune decision
__global__ __launch_bounds__(256)
void decide_kernel(const float* __restrict__ jac,
                   int* __restrict__ nTokPtr, int* __restrict__ nTokNextPtr,
                   int* __restrict__ keepIdx, float* __restrict__ prevMassPtr,
                   int* __restrict__ prevValidPtr) {
    const int nTok = *nTokPtr;
    const int N = nTok - 1;
    const int tid = threadIdx.x;
    if (N <= 16) {
        if (tid == 0) { *prevValidPtr = 0; *nTokNextPtr = nTok; }
        for (int t = tid; t < nTok; t += 256) keepIdx[t] = t;
        return;
    }
    __shared__ float impF[NPATCH];
    __shared__ int   sel[NPATCH];
    __shared__ int   s_next;
    for (int j = tid; j < N; j += 256) {
        double s = 0.0;
        for (int r = 0; r < BB * NHEAD; r++) s += (double)jac[(size_t)r * NPATCH + j];
        impF[j] = (float)(s * (1.0 / 384.0));
    }
    __syncthreads();
    if (tid == 0) {
        double ms = 0.0;
        for (int j = 0; j < N; j++) ms += (double)impF[j];
        float massF = (float)ms;
        float meanF = (float)(ms / (double)N);
        double vs = 0.0;
        for (int j = 0; j < N; j++) { double d = (double)impF[j] - (double)meanF; vs += d * d; }
        float stdF = (float)sqrt(vs / (double)N);
        float rho = stdF / (meanF + 1e-6f);
        int nnext;
        if (*prevValidPtr != 0) {
            float pm = *prevMassPtr;
            float drift = fabsf(massF - pm) / (pm + 1e-6f);
            float kr = 1.0f - 0.01f * rho * (1.0f + drift);
            kr = fminf(fmaxf(kr, 0.0f), 1.0f);
            int t = (int)((double)N * (double)kr);   // Python int(): trunc
            nnext = t < 16 ? 16 : t;
        } else {
            nnext = N;
        }
        *prevMassPtr = massF;
        *prevValidPtr = 1;
        s_next = nnext;
        *nTokNextPtr = nnext + 1;
    }
    __syncthreads();
    int nnext = s_next;
    if (nnext < N) {
        for (int j = tid; j < N; j += 256) {
            float vj = impF[j];
            int rank = 0;
            for (int i = 0; i < N; i++) {
                float vi = impF[i];
                rank += (vi > vj || (vi == vj && i < j)) ? 1 : 0;
            }
            sel[j] = (rank < nnext) ? 1 : 0;
        }
        __syncthreads();
        if (tid == 0) {
            int c = 1;
            keepIdx[0] = 0;
            for (int j = 0; j < N; j++) if (sel[j]) keepIdx[c++] = j + 1;
        }
    } else {
        for (int t = tid; t < nTok; t += 256) keepIdx[t] = t;
    }
}

// ---------------------------------------------------------------- gather
__global__ __launch_bounds__(192)
void gather_kernel(const float* __restrict__ src, float* __restrict__ dst,
                   const int* __restrict__ keepIdx,
                   const int* __restrict__ nTokNextPtr, int* __restrict__ nTokPtr) {
    int nn = *nTokNextPtr;
    int m = blockIdx.x;
    int b = m / NTOK, t = m - b * NTOK;
    if (t < nn) {
        int s = keepIdx[t];
        const float4* sp = (const float4*)(src + ((size_t)b * NTOK + s) * DMODEL);
        float4* dp = (float4*)(dst + ((size_t)b * NTOK + t) * DMODEL);
        dp[threadIdx.x] = sp[threadIdx.x];
    }
    if (m == 0 && threadIdx.x == 0) *nTokPtr = nn;
}

// ---------------------------------------------------------------- head
__global__ __launch_bounds__(256)
void head_kernel(const float* __restrict__ lnC, const float* __restrict__ W,
                 const float* __restrict__ hb, float* __restrict__ out) {
    int b = blockIdx.x;
    int n = blockIdx.y * 256 + threadIdx.x;
    __shared__ float xs[DMODEL];
    for (int i = threadIdx.x; i < DMODEL; i += 256) xs[i] = lnC[(size_t)b * DMODEL + i];
    __syncthreads();
    if (n < NCLASS) {
        float acc = hb[n];
        for (int d = 0; d < DMODEL; d++) acc = fmaf(xs[d], W[(size_t)d * NCLASS + n], acc);
        out[(size_t)b * NCLASS + n] = acc;
    }
}

// ================================================================= launch
extern "C" void kernel_launch(void* const* d_in, const int* in_sizes, int n_in,
                              void* d_out, int out_size, void* d_ws, size_t ws_size,
                              hipStream_t stream) {
    const float* x       = (const float*)d_in[0];
    const float* patch_w = (const float*)d_in[1];
    const float* patch_b = (const float*)d_in[2];
    const float* cls_tok = (const float*)d_in[3];
    const float* pos     = (const float*)d_in[4];
    const float* ln1_w   = (const float*)d_in[5];
    const float* ln1_b   = (const float*)d_in[6];
    const float* qkv_w   = (const float*)d_in[7];
    const float* qkv_b   = (const float*)d_in[8];
    const float* proj_w  = (const float*)d_in[9];
    const float* proj_b  = (const float*)d_in[10];
    const float* ln2_w   = (const float*)d_in[11];
    const float* ln2_b   = (const float*)d_in[12];
    const float* fc1_w   = (const float*)d_in[13];
    const float* fc1_b   = (const float*)d_in[14];
    const float* fc2_w   = (const float*)d_in[15];
    const float* fc2_b   = (const float*)d_in[16];
    const float* norm_w  = (const float*)d_in[17];
    const float* norm_b  = (const float*)d_in[18];
    const float* head_w  = (const float*)d_in[19];
    const float* head_b  = (const float*)d_in[20];
    float* out = (float*)d_out;

    char* ws = (char*)d_ws;
    size_t off = 0;
    auto alloc = [&](size_t nfl) {
        float* p = (float*)(ws + off);
        off += ((nfl * 4 + 255) / 256) * 256;
        return p;
    };
    float* tokA = alloc((size_t)BB * NTOK * DMODEL);
    float* tokB = alloc((size_t)BB * NTOK * DMODEL);
    float* xn   = alloc((size_t)BB * NTOK * DMODEL);
    float* qkvb = alloc((size_t)BB * NTOK * 3 * DMODEL);
    float* hbuf = alloc((size_t)BB * NTOK * 4 * DMODEL);   // also attnout (disjoint lifetime)
    float* attnout = hbuf;
    float* wT   = alloc((size_t)768 * 768);
    float* jac  = alloc((size_t)BB * NHEAD * NPATCH);
    float* lnC  = alloc((size_t)BB * DMODEL);
    float* prevMass = alloc(8);
    int* ints = (int*)(ws + off);
    int* nTokP = ints; int* nTokNextP = ints + 1; int* prevValidP = ints + 2;
    int* keepIdx = ints + 4;

    dim3 blk(256);
    state_init<<<dim3(1), dim3(1), 0, stream>>>(nTokP, prevValidP);
    transpose768<<<dim3(24, 24), dim3(32, 8), 0, stream>>>(patch_w, wT);
    cls_init<<<dim3(BB), blk, 0, stream>>>(cls_tok, pos, tokA);
    gemm_patch<<<dim3(49, 6), blk, 0, stream>>>(x, wT, patch_b, pos, tokA);

    float* bufs[2] = {tokA, tokB};
    const int gm = (MTOT + 127) / 128;   // 50
    for (int l = 0; l < NLAYER; l++) {
        float* cur = bufs[l & 1];
        float* nxt = bufs[(l + 1) & 1];
        ln_tok<<<dim3(MTOT), blk, 0, stream>>>(cur, xn, ln1_w + l * 768, ln1_b + l * 768, nTokP);
        gemm_tok<0><<<dim3(gm, 18), blk, 0, stream>>>(
            xn, 768, qkv_w + (size_t)l * 768 * 2304, 2304, qkv_b + (size_t)l * 2304,
            nullptr, qkvb, 2304, 768, MTOT, nTokP);
        attn_kernel<<<dim3(BB * NHEAD), blk, 0, stream>>>(qkvb, attnout, jac, nTokP);
        gemm_tok<1><<<dim3(gm, 6), blk, 0, stream>>>(
            attnout, 768, proj_w + (size_t)l * 768 * 768, 768, proj_b + (size_t)l * 768,
            cur, cur, 768, 768, MTOT, nTokP);
        ln_tok<<<dim3(MTOT), blk, 0, stream>>>(cur, xn, ln2_w + l * 768, ln2_b + l * 768, nTokP);
        gemm_tok<2><<<dim3(gm, 24), blk, 0, stream>>>(
            xn, 768, fc1_w + (size_t)l * 768 * 3072, 3072, fc1_b + (size_t)l * 3072,
            nullptr, hbuf, 3072, 768, MTOT, nTokP);
        gemm_tok<1><<<dim3(gm, 6), blk, 0, stream>>>(
            hbuf, 3072, fc2_w + (size_t)l * 3072 * 768, 768, fc2_b + (size_t)l * 768,
            cur, cur, 768, 3072, MTOT, nTokP);
        decide_kernel<<<dim3(1), blk, 0, stream>>>(jac, nTokP, nTokNextP, keepIdx,
                                                   prevMass, prevValidP);
        gather_kernel<<<dim3(MTOT), dim3(192), 0, stream>>>(cur, nxt, keepIdx, nTokNextP, nTokP);
    }
    ln_cls<<<dim3(BB), blk, 0, stream>>>(bufs[0], lnC, norm_w, norm_b);
    head_kernel<<<dim3(BB, 4), blk, 0, stream>>>(lnC, head_w, head_b, out);
}

// Round 2
// 9721.082 us; speedup vs baseline: 2.6790x; 2.6790x over previous
//
#include <hip/hip_runtime.h>
#include <math.h>

#define DEV_INLINE __device__ __forceinline__

constexpr int BB     = 32;
constexpr int DMODEL = 768;
constexpr int NHEAD  = 12;
constexpr int NPATCH = 196;
constexpr int NTOK   = 197;
constexpr int NLAYER = 12;
constexpr int NCLASS = 1000;
constexpr int MTOT   = BB * NTOK;   // 6304

typedef __attribute__((ext_vector_type(4))) float f32x4;
typedef __attribute__((ext_vector_type(8))) short bf16x8;
typedef __attribute__((ext_vector_type(4))) short short4v;

// fp32 -> (hi, lo) bf16 pair, both RNE. x ~= hi + lo with ~17 mantissa bits.
DEV_INLINE void split2(float x, unsigned short& hi, unsigned short& lo) {
    unsigned u = __builtin_bit_cast(unsigned, x);
    unsigned r = (u + 0x7FFFu + ((u >> 16) & 1u)) >> 16;
    hi = (unsigned short)r;
    float fh = __builtin_bit_cast(float, r << 16);
    float l = x - fh;
    unsigned ul = __builtin_bit_cast(unsigned, l);
    lo = (unsigned short)((ul + 0x7FFFu + ((ul >> 16) & 1u)) >> 16);
}

DEV_INLINE float block_reduce_sum(float v, float* sbuf) {
    #pragma unroll
    for (int off = 32; off > 0; off >>= 1) v += __shfl_down(v, off, 64);
    int lane = threadIdx.x & 63, w = threadIdx.x >> 6;
    __syncthreads();
    if (lane == 0) sbuf[w] = v;
    __syncthreads();
    return sbuf[0] + sbuf[1] + sbuf[2] + sbuf[3];
}

// ---------------------------------------------------------------- state init
__global__ void state_init(int* nTokPtr, int* prevValidPtr) {
    *nTokPtr = NTOK;
    *prevValidPtr = 0;
}

// ---------------------------------------------------------------- CLS row
__global__ __launch_bounds__(256)
void cls_init(const float* __restrict__ cls, const float* __restrict__ pos,
              float* __restrict__ tok) {
    int b = blockIdx.x;
    for (int i = threadIdx.x; i < DMODEL; i += 256)
        tok[(size_t)b * NTOK * DMODEL + i] = cls[i] + pos[i];
}

// ------------------------------------------------- weight convert (no transpose)
// patch_w is [N=768][K=768] already; elementwise fp32 -> hi/lo bf16
__global__ __launch_bounds__(256)
void wconv_nt(const float* __restrict__ src, unsigned short* __restrict__ hi,
              unsigned short* __restrict__ lo, int n) {
    int i = blockIdx.x * 256 + threadIdx.x;
    if (i < n) { unsigned short h, l; split2(src[i], h, l); hi[i] = h; lo[i] = l; }
}

// ------------------------------------------------- per-layer weight convert
// transposes [K][N] fp32 -> [N][K] bf16 hi/lo for qkv/proj/fc1/fc2, packed.
constexpr size_t WOFF_QKV  = 0;
constexpr size_t WOFF_PROJ = (size_t)768 * 2304;
constexpr size_t WOFF_FC1  = WOFF_PROJ + (size_t)768 * 768;
constexpr size_t WOFF_FC2  = WOFF_FC1 + (size_t)768 * 3072;
constexpr size_t WTOTAL    = WOFF_FC2 + (size_t)3072 * 768;   // 7,077,888

__global__ __launch_bounds__(256)
void wconv_layer(const float* __restrict__ qkvw, const float* __restrict__ projw,
                 const float* __restrict__ fc1w, const float* __restrict__ fc2w,
                 unsigned short* __restrict__ hi, unsigned short* __restrict__ lo) {
    __shared__ float tile[32][33];
    int bid = blockIdx.x;
    const float* src; int Kd, Nd; size_t dofs;
    if (bid < 1728)      { src = qkvw;  Kd = 768;  Nd = 2304; dofs = WOFF_QKV; }
    else if (bid < 2304) { bid -= 1728; src = projw; Kd = 768;  Nd = 768;  dofs = WOFF_PROJ; }
    else if (bid < 4608) { bid -= 2304; src = fc1w;  Kd = 768;  Nd = 3072; dofs = WOFF_FC1; }
    else                 { bid -= 4608; src = fc2w;  Kd = 3072; Nd = 768;  dofs = WOFF_FC2; }
    int ntx = Nd / 32;
    int n0 = (bid % ntx) * 32, k0 = (bid / ntx) * 32;
    int tx = threadIdx.x & 31, ty = threadIdx.x >> 5;   // 32 x 8
    #pragma unroll
    for (int i = 0; i < 32; i += 8)
        tile[ty + i][tx] = src[(size_t)(k0 + ty + i) * Nd + n0 + tx];
    __syncthreads();
    #pragma unroll
    for (int i = 0; i < 32; i += 8) {
        float v = tile[tx][ty + i];   // src[k0+tx][n0+ty+i]
        unsigned short h, l; split2(v, h, l);
        size_t o = dofs + (size_t)(n0 + ty + i) * Kd + k0 + tx;
        hi[o] = h; lo[o] = l;
    }
}

// ------------------------------------------------------------- MFMA GEMM
// C[m,n] = A[m,:] . W[:,n] via split-bf16 (hi+lo), W pre-converted to [N][K].
// ASRC: 0 = plain fp32 A [m][lda], 1 = im2col of x (patch embed)
// EPI : 0 = +bias, 1 = +bias+resid, 2 = +bias,GELU, 3 = patch (+bias+pos, scatter)
template<int ASRC, int EPI>
__global__ __launch_bounds__(256)
void mfma_gemm(const float* __restrict__ A, int lda,
               const unsigned short* __restrict__ Whi,
               const unsigned short* __restrict__ Wlo,
               const float* __restrict__ bias,
               const float* __restrict__ resid,     // resid (EPI1) or pos (EPI3)
               float* __restrict__ C, int ldc,
               int K, int Mtot, const int* __restrict__ nTokPtr) {
    const int nTok = (ASRC == 0) ? *nTokPtr : NTOK;
    const int m0 = blockIdx.x * 128, n0 = blockIdx.y * 128;
    if (m0 >= Mtot) return;
    if (ASRC == 0) {
        int ts = m0 % NTOK;
        if (!(ts < nTok || ts + 128 > NTOK)) return;   // whole tile pruned
    }
    __shared__ unsigned short Ah[128 * 32], Al[128 * 32];
    __shared__ unsigned short Bh[128 * 32], Bl[128 * 32];
    const int tid = threadIdx.x;
    const int lane = tid & 63, wid = tid >> 6;
    const int wm = wid >> 1, wn = wid & 1;
    const int fr = lane & 15, fg = lane >> 4;

    f32x4 acc[4][4];
    #pragma unroll
    for (int i = 0; i < 4; ++i)
        #pragma unroll
        for (int j = 0; j < 4; ++j) acc[i][j] = (f32x4){0.f, 0.f, 0.f, 0.f};

    // A staging precompute: thread t covers row (t>>3)+32p, float4 at k = fk
    int srow[4]; bool sval[4]; size_t sbase[4];
    #pragma unroll
    for (int p = 0; p < 4; ++p) {
        int rl = (tid >> 3) + p * 32;
        int arow = m0 + rl;
        bool v = arow < Mtot;
        if (ASRC == 0) v = v && (arow % NTOK) < nTok;
        srow[p] = rl; sval[p] = v;
        if (ASRC == 0) sbase[p] = (size_t)arow * lda;
        else {
            int b = arow / NPATCH, pp = arow - b * NPATCH;
            int py = pp / 14, px = pp - py * 14;
            sbase[p] = (size_t)b * (3 * 224 * 224) + (size_t)(py * 16) * 224 + px * 16;
        }
    }
    const int fk = (tid & 7) * 4;
    const int bcol = tid >> 2, bck = tid & 3;

    for (int kb = 0; kb < K; kb += 32) {
        // ---- stage A (fp32 -> split bf16, XOR-swizzled 16B chunks)
        #pragma unroll
        for (int p = 0; p < 4; ++p) {
            float4 v = make_float4(0.f, 0.f, 0.f, 0.f);
            if (sval[p]) {
                size_t off;
                if (ASRC == 0) off = sbase[p] + kb + fk;
                else {
                    int k = kb + fk;
                    off = sbase[p] + (size_t)(k >> 8) * (224 * 224)
                        + (size_t)((k >> 4) & 15) * 224 + (k & 15);
                }
                v = *(const float4*)(A + off);
            }
            unsigned short h0,l0,h1,l1,h2,l2,h3,l3;
            split2(v.x,h0,l0); split2(v.y,h1,l1); split2(v.z,h2,l2); split2(v.w,h3,l3);
            int row = srow[p];
            int c = fk >> 3, half = (fk >> 2) & 1;
            int off16 = row * 32 + ((c ^ ((row >> 1) & 3)) << 3) + half * 4;
            short4v hh = {(short)h0, (short)h1, (short)h2, (short)h3};
            short4v ll = {(short)l0, (short)l1, (short)l2, (short)l3};
            *(short4v*)&Ah[off16] = hh;
            *(short4v*)&Al[off16] = ll;
        }
        // ---- stage B (already bf16 [N][K]; 2 passes of 64 cols)
        #pragma unroll
        for (int p = 0; p < 2; ++p) {
            int col = bcol + p * 64;
            size_t goff = (size_t)(n0 + col) * K + kb + bck * 8;
            int off16 = col * 32 + ((bck ^ ((col >> 1) & 3)) << 3);
            *(bf16x8*)&Bh[off16] = *(const bf16x8*)(Whi + goff);
            *(bf16x8*)&Bl[off16] = *(const bf16x8*)(Wlo + goff);
        }
        __syncthreads();
        // ---- fragments + 48 MFMAs (hi*hi + hi*lo + lo*hi)
        bf16x8 ah[4], al[4], bh[4], bl[4];
        #pragma unroll
        for (int i = 0; i < 4; ++i) {
            int row = wm * 64 + i * 16 + fr;
            int aoff = row * 32 + ((fg ^ ((row >> 1) & 3)) << 3);
            ah[i] = *(const bf16x8*)&Ah[aoff];
            al[i] = *(const bf16x8*)&Al[aoff];
            int col = wn * 64 + i * 16 + fr;
            int boff = col * 32 + ((fg ^ ((col >> 1) & 3)) << 3);
            bh[i] = *(const bf16x8*)&Bh[boff];
            bl[i] = *(const bf16x8*)&Bl[boff];
        }
        #pragma unroll
        for (int i = 0; i < 4; ++i)
            #pragma unroll
            for (int j = 0; j < 4; ++j) {
                acc[i][j] = __builtin_amdgcn_mfma_f32_16x16x32_bf16(ah[i], bh[j], acc[i][j], 0, 0, 0);
                acc[i][j] = __builtin_amdgcn_mfma_f32_16x16x32_bf16(ah[i], bl[j], acc[i][j], 0, 0, 0);
                acc[i][j] = __builtin_amdgcn_mfma_f32_16x16x32_bf16(al[i], bh[j], acc[i][j], 0, 0, 0);
            }
        __syncthreads();
    }
    // ---- epilogue (C/D layout: col = lane&15, row = (lane>>4)*4 + e)
    #pragma unroll
    for (int i = 0; i < 4; ++i) {
        #pragma unroll
        for (int j = 0; j < 4; ++j) {
            #pragma unroll
            for (int e = 0; e < 4; ++e) {
                int m = m0 + wm * 64 + i * 16 + fg * 4 + e;
                int n = n0 + wn * 64 + j * 16 + fr;
                if (m >= Mtot) continue;
                if (ASRC == 0 && (m % NTOK) >= nTok) continue;
                float v = acc[i][j][e] + bias[n];
                if constexpr (EPI == 1) v += resid[(size_t)m * ldc + n];
                if constexpr (EPI == 2) v = 0.5f * v * (1.0f + erff(v * 0.70710678118654752f));
                if constexpr (EPI == 3) {
                    int b = m / NPATCH, pp = m - b * NPATCH;
                    v += resid[(size_t)(1 + pp) * DMODEL + n];   // pos embed
                    C[((size_t)b * NTOK + 1 + pp) * DMODEL + n] = v;
                } else {
                    C[(size_t)m * ldc + n] = v;
                }
            }
        }
    }
}

// ---------------------------------------------------------------- LayerNorm
DEV_INLINE void ln_row(const float* __restrict__ x, float* __restrict__ y,
                       const float* __restrict__ w, const float* __restrict__ b,
                       float* sbuf) {
    int tid = threadIdx.x;
    float v[3];
    #pragma unroll
    for (int i = 0; i < 3; i++) v[i] = x[tid + i * 256];
    float mu = block_reduce_sum(v[0] + v[1] + v[2], sbuf) * (1.0f / 768.0f);
    float d2 = 0.f;
    #pragma unroll
    for (int i = 0; i < 3; i++) { float d = v[i] - mu; d2 = fmaf(d, d, d2); }
    float var = block_reduce_sum(d2, sbuf) * (1.0f / 768.0f);
    float rstd = rsqrtf(var + 1e-6f);
    #pragma unroll
    for (int i = 0; i < 3; i++) {
        int idx = tid + i * 256;
        y[idx] = (v[i] - mu) * rstd * w[idx] + b[idx];
    }
}

__global__ __launch_bounds__(256)
void ln_tok(const float* __restrict__ X, float* __restrict__ Y,
            const float* __restrict__ w, const float* __restrict__ b,
            const int* __restrict__ nTokPtr) {
    int m = blockIdx.x;
    if ((m % NTOK) >= *nTokPtr) return;
    __shared__ float sbuf[4];
    ln_row(X + (size_t)m * DMODEL, Y + (size_t)m * DMODEL, w, b, sbuf);
}

__global__ __launch_bounds__(256)
void ln_cls(const float* __restrict__ X, float* __restrict__ Y,
            const float* __restrict__ w, const float* __restrict__ b) {
    int bb = blockIdx.x;
    __shared__ float sbuf[4];
    ln_row(X + (size_t)bb * NTOK * DMODEL, Y + (size_t)bb * DMODEL, w, b, sbuf);
}

// ---------------------------------------------------------------- attention v2
// flash-style: grid (b*h, 7 q-tiles of 32). K/V tiles staged in LDS, online
// softmax (running m,l), O in registers. qt0 block also emits jac for decide.
__global__ __launch_bounds__(256)
void attn_v2(const float* __restrict__ qkv, float* __restrict__ attnout,
             float* __restrict__ jacg, const int* __restrict__ nTokPtr) {
    const int nTok = *nTokPtr;
    const int bh = blockIdx.x;
    const int b = bh / NHEAD, h = bh % NHEAD;
    const int q0 = blockIdx.y * 32;
    if (q0 >= nTok) return;
    __shared__ float Qs[32][68];
    __shared__ float KVs[64][68];
    __shared__ float Ss[32][67];
    __shared__ float mrow[32], lrow[32], frow[32];
    __shared__ float s0row[208];
    __shared__ float vnrow[208];
    const int tid = threadIdx.x;
    const float* base = qkv + (size_t)b * NTOK * 2304 + (size_t)h * 64;

    {   // stage Q tile (rows q0..q0+31)
        int r = tid >> 3, fc = tid & 7;
        int q = q0 + r;
        #pragma unroll
        for (int p = 0; p < 2; ++p) {
            float4 v = make_float4(0.f, 0.f, 0.f, 0.f);
            if (q < nTok) v = *(const float4*)(base + (size_t)q * 2304 + (fc + p * 8) * 4);
            *(float4*)&Qs[r][(fc + p * 8) * 4] = v;
        }
    }
    if (tid < 32) { mrow[tid] = -INFINITY; lrow[tid] = 0.f; }

    float o[2][4] = {{0.f,0.f,0.f,0.f},{0.f,0.f,0.f,0.f}};
    const int qq = tid & 15, dd = tid >> 4;   // (q,d) mapping for PV/output
    const int q2 = qq * 2;
    const int njt = (nTok + 63) >> 6;

    for (int jt = 0; jt < njt; ++jt) {
        const int jb = jt * 64;
        __syncthreads();                         // prev PV done; Q/init visible
        {   // stage K tile
            int jr = tid >> 2, fc = tid & 3;
            int j = jb + jr;
            const float* krow = base + (size_t)j * 2304 + 768;
            #pragma unroll
            for (int p = 0; p < 4; ++p) {
                float4 v = make_float4(0.f, 0.f, 0.f, 0.f);
                if (j < nTok) v = *(const float4*)(krow + (fc + p * 4) * 4);
                *(float4*)&KVs[jr][(fc + p * 4) * 4] = v;
            }
        }
        __syncthreads();
        {   // QK^T: thread = (qq: 2 q rows, jj: 4 j cols), float4 over d
            const int jj = tid >> 4;
            float sacc[2][4] = {{0,0,0,0},{0,0,0,0}};
            #pragma unroll 4
            for (int d0 = 0; d0 < 16; ++d0) {
                float4 qa = *(const float4*)&Qs[q2][d0 * 4];
                float4 qb = *(const float4*)&Qs[q2 + 1][d0 * 4];
                #pragma unroll
                for (int r = 0; r < 4; ++r) {
                    float4 kv = *(const float4*)&KVs[jj * 4 + r][d0 * 4];
                    sacc[0][r] = fmaf(qa.x, kv.x, sacc[0][r]);
                    sacc[0][r] = fmaf(qa.y, kv.y, sacc[0][r]);
                    sacc[0][r] = fmaf(qa.z, kv.z, sacc[0][r]);
                    sacc[0][r] = fmaf(qa.w, kv.w, sacc[0][r]);
                    sacc[1][r] = fmaf(qb.x, kv.x, sacc[1][r]);
                    sacc[1][r] = fmaf(qb.y, kv.y, sacc[1][r]);
                    sacc[1][r] = fmaf(qb.z, kv.z, sacc[1][r]);
                    sacc[1][r] = fmaf(qb.w, kv.w, sacc[1][r]);
                }
            }
            #pragma unroll
            for (int s = 0; s < 2; ++s) {
                int q = q0 + q2 + s;
                #pragma unroll
                for (int r = 0; r < 4; ++r) {
                    int j = jb + jj * 4 + r;
                    float sv = (j < nTok && q < nTok) ? sacc[s][r] * 0.125f : -INFINITY;
                    Ss[q2 + s][jj * 4 + r] = sv;
                    if (q0 == 0 && qq == 0 && s == 0 && j < nTok) s0row[j] = sv;
                }
            }
        }
        __syncthreads();
        // online softmax update, thread-per-row
        if (tid < 32) {
            int q = q0 + tid;
            if (q < nTok) {
                int jn = min(64, nTok - jb);
                float mt = -INFINITY;
                for (int j = 0; j < jn; ++j) mt = fmaxf(mt, Ss[tid][j]);
                float mnew = fmaxf(mrow[tid], mt);
                float f = expf(mrow[tid] - mnew);
                float sum = 0.f;
                for (int j = 0; j < jn; ++j) {
                    float p = expf(Ss[tid][j] - mnew);
                    Ss[tid][j] = p; sum += p;
                }
                for (int j = jn; j < 64; ++j) Ss[tid][j] = 0.f;
                lrow[tid] = lrow[tid] * f + sum;
                mrow[tid] = mnew;
                frow[tid] = f;
            }
        }
        {   // stage V tile (overwrites K; K fully consumed above)
            int jr = tid >> 2, fc = tid & 3;
            int j = jb + jr;
            const float* vrow = base + (size_t)j * 2304 + 1536;
            #pragma unroll
            for (int p = 0; p < 4; ++p) {
                float4 v = make_float4(0.f, 0.f, 0.f, 0.f);
                if (j < nTok) v = *(const float4*)(vrow + (fc + p * 4) * 4);
                *(float4*)&KVs[jr][(fc + p * 4) * 4] = v;
            }
        }
        __syncthreads();
        if (q0 == 0 && tid < 64) {   // ||v_j|| for jac (qt0 only)
            int j = jb + tid;
            if (j < nTok) {
                float s = 0.f;
                for (int d = 0; d < 64; ++d) { float v = KVs[tid][d]; s = fmaf(v, v, s); }
                vnrow[j] = sqrtf(s);
            }
        }
        {   // PV accumulate with rescale
            float f0 = frow[q2], f1 = frow[q2 + 1];
            #pragma unroll
            for (int r = 0; r < 4; ++r) { o[0][r] *= f0; o[1][r] *= f1; }
            for (int j = 0; j < 64; ++j) {
                float p0 = Ss[q2][j], p1 = Ss[q2 + 1][j];
                float4 vv = *(const float4*)&KVs[j][dd * 4];
                o[0][0] = fmaf(p0, vv.x, o[0][0]);
                o[0][1] = fmaf(p0, vv.y, o[0][1]);
                o[0][2] = fmaf(p0, vv.z, o[0][2]);
                o[0][3] = fmaf(p0, vv.w, o[0][3]);
                o[1][0] = fmaf(p1, vv.x, o[1][0]);
                o[1][1] = fmaf(p1, vv.y, o[1][1]);
                o[1][2] = fmaf(p1, vv.z, o[1][2]);
                o[1][3] = fmaf(p1, vv.w, o[1][3]);
            }
        }
    }
    __syncthreads();
    // write O / l
    #pragma unroll
    for (int s = 0; s < 2; ++s) {
        int q = q0 + q2 + s;
        if (q < nTok) {
            float inv = 1.0f / lrow[q2 + s];
            float4 ov = make_float4(o[s][0] * inv, o[s][1] * inv, o[s][2] * inv, o[s][3] * inv);
            *(float4*)(attnout + ((size_t)b * NTOK + q) * DMODEL + (size_t)h * 64 + dd * 4) = ov;
        }
    }
    // jac from final CLS softmax (qt0 block)
    if (q0 == 0) {
        float m0f = mrow[0], l0 = lrow[0];
        for (int j = 1 + tid; j < nTok; j += 256)
            jacg[(size_t)bh * NPATCH + (j - 1)] = (expf(s0row[j] - m0f) / l0) * vnrow[j];
    }
}

// ------------------------------------------------------- prune decision
__global__ __launch_bounds__(256)
void decide_kernel(const float* __restrict__ jac,
                   int* __restrict__ nTokPtr, int* __restrict__ nTokNextPtr,
                   int* __restrict__ keepIdx, float* __restrict__ prevMassPtr,
                   int* __restrict__ prevValidPtr) {
    const int nTok = *nTokPtr;
    const int N = nTok - 1;
    const int tid = threadIdx.x;
    if (N <= 16) {
        if (tid == 0) { *prevValidPtr = 0; *nTokNextPtr = nTok; }
        for (int t = tid; t < nTok; t += 256) keepIdx[t] = t;
        return;
    }
    __shared__ float impF[NPATCH];
    __shared__ int   sel[NPATCH];
    __shared__ int   s_next;
    for (int j = tid; j < N; j += 256) {
        double s = 0.0;
        for (int r = 0; r < BB * NHEAD; r++) s += (double)jac[(size_t)r * NPATCH + j];
        impF[j] = (float)(s * (1.0 / 384.0));
    }
    __syncthreads();
    if (tid == 0) {
        double ms = 0.0;
        for (int j = 0; j < N; j++) ms += (double)impF[j];
        float massF = (float)ms;
        float meanF = (float)(ms / (double)N);
        double vs = 0.0;
        for (int j = 0; j < N; j++) { double d = (double)impF[j] - (double)meanF; vs += d * d; }
        float stdF = (float)sqrt(vs / (double)N);
        float rho = stdF / (meanF + 1e-6f);
        int nnext;
        if (*prevValidPtr != 0) {
            float pm = *prevMassPtr;
            float drift = fabsf(massF - pm) / (pm + 1e-6f);
            float kr = 1.0f - 0.01f * rho * (1.0f + drift);
            kr = fminf(fmaxf(kr, 0.0f), 1.0f);
            int t = (int)((double)N * (double)kr);
            nnext = t < 16 ? 16 : t;
        } else {
            nnext = N;
        }
        *prevMassPtr = massF;
        *prevValidPtr = 1;
        s_next = nnext;
        *nTokNextPtr = nnext + 1;
    }
    __syncthreads();
    int nnext = s_next;
    if (nnext < N) {
        for (int j = tid; j < N; j += 256) {
            float vj = impF[j];
            int rank = 0;
            for (int i = 0; i < N; i++) {
                float vi = impF[i];
                rank += (vi > vj || (vi == vj && i < j)) ? 1 : 0;
            }
            sel[j] = (rank < nnext) ? 1 : 0;
        }
        __syncthreads();
        if (tid == 0) {
            int c = 1;
            keepIdx[0] = 0;
            for (int j = 0; j < N; j++) if (sel[j]) keepIdx[c++] = j + 1;
        }
    } else {
        for (int t = tid; t < nTok; t += 256) keepIdx[t] = t;
    }
}

// ---------------------------------------------------------------- gather
__global__ __launch_bounds__(192)
void gather_kernel(const float* __restrict__ src, float* __restrict__ dst,
                   const int* __restrict__ keepIdx,
                   const int* __restrict__ nTokNextPtr, int* __restrict__ nTokPtr) {
    int nn = *nTokNextPtr;
    int m = blockIdx.x;
    int b = m / NTOK, t = m - b * NTOK;
    if (t < nn) {
        int s = keepIdx[t];
        const float4* sp = (const float4*)(src + ((size_t)b * NTOK + s) * DMODEL);
        float4* dp = (float4*)(dst + ((size_t)b * NTOK + t) * DMODEL);
        dp[threadIdx.x] = sp[threadIdx.x];
    }
    if (m == 0 && threadIdx.x == 0) *nTokPtr = nn;
}

// ---------------------------------------------------------------- head
__global__ __launch_bounds__(256)
void head_kernel(const float* __restrict__ lnC, const float* __restrict__ W,
                 const float* __restrict__ hb, float* __restrict__ out) {
    int b = blockIdx.x;
    int n = blockIdx.y * 256 + threadIdx.x;
    __shared__ float xs[DMODEL];
    for (int i = threadIdx.x; i < DMODEL; i += 256) xs[i] = lnC[(size_t)b * DMODEL + i];
    __syncthreads();
    if (n < NCLASS) {
        float acc = hb[n];
        for (int d = 0; d < DMODEL; d++) acc = fmaf(xs[d], W[(size_t)d * NCLASS + n], acc);
        out[(size_t)b * NCLASS + n] = acc;
    }
}

// ================================================================= launch
extern "C" void kernel_launch(void* const* d_in, const int* in_sizes, int n_in,
                              void* d_out, int out_size, void* d_ws, size_t ws_size,
                              hipStream_t stream) {
    const float* x       = (const float*)d_in[0];
    const float* patch_w = (const float*)d_in[1];
    const float* patch_b = (const float*)d_in[2];
    const float* cls_tok = (const float*)d_in[3];
    const float* pos     = (const float*)d_in[4];
    const float* ln1_w   = (const float*)d_in[5];
    const float* ln1_b   = (const float*)d_in[6];
    const float* qkv_w   = (const float*)d_in[7];
    const float* qkv_b   = (const float*)d_in[8];
    const float* proj_w  = (const float*)d_in[9];
    const float* proj_b  = (const float*)d_in[10];
    const float* ln2_w   = (const float*)d_in[11];
    const float* ln2_b   = (const float*)d_in[12];
    const float* fc1_w   = (const float*)d_in[13];
    const float* fc1_b   = (const float*)d_in[14];
    const float* fc2_w   = (const float*)d_in[15];
    const float* fc2_b   = (const float*)d_in[16];
    const float* norm_w  = (const float*)d_in[17];
    const float* norm_b  = (const float*)d_in[18];
    const float* head_w  = (const float*)d_in[19];
    const float* head_b  = (const float*)d_in[20];
    float* out = (float*)d_out;

    char* ws = (char*)d_ws;
    size_t off = 0;
    auto alloc = [&](size_t nbytes) {
        char* p = ws + off;
        off += ((nbytes + 255) / 256) * 256;
        return p;
    };
    float* tokA = (float*)alloc((size_t)BB * NTOK * DMODEL * 4);
    float* tokB = (float*)alloc((size_t)BB * NTOK * DMODEL * 4);
    float* xn   = (float*)alloc((size_t)BB * NTOK * DMODEL * 4);
    float* qkvb = (float*)alloc((size_t)BB * NTOK * 3 * DMODEL * 4);
    float* hbuf = (float*)alloc((size_t)BB * NTOK * 4 * DMODEL * 4);  // also attnout
    float* attnout = hbuf;
    float* jac  = (float*)alloc((size_t)BB * NHEAD * NPATCH * 4);
    float* lnC  = (float*)alloc((size_t)BB * DMODEL * 4);
    float* prevMass = (float*)alloc(32);
    unsigned short* whi = (unsigned short*)alloc(WTOTAL * 2);
    unsigned short* wlo = (unsigned short*)alloc(WTOTAL * 2);
    int* ints = (int*)alloc(1024);
    int* nTokP = ints; int* nTokNextP = ints + 1; int* prevValidP = ints + 2;
    int* keepIdx = ints + 4;

    dim3 blk(256);
    state_init<<<dim3(1), dim3(1), 0, stream>>>(nTokP, prevValidP);
    // patch weights: [N][K] already, straight convert into whi/wlo base
    wconv_nt<<<dim3((768 * 768 + 255) / 256), blk, 0, stream>>>(patch_w, whi, wlo, 768 * 768);
    cls_init<<<dim3(BB), blk, 0, stream>>>(cls_tok, pos, tokA);
    mfma_gemm<1, 3><<<dim3(49, 6), blk, 0, stream>>>(
        x, 0, whi, wlo, patch_b, pos, tokA, DMODEL, 768, BB * NPATCH, nTokP);

    float* bufs[2] = {tokA, tokB};
    const int gm = (MTOT + 127) / 128;   // 50
    for (int l = 0; l < NLAYER; l++) {
        float* cur = bufs[l & 1];
        float* nxt = bufs[(l + 1) & 1];
        wconv_layer<<<dim3(6912), blk, 0, stream>>>(
            qkv_w + (size_t)l * 768 * 2304, proj_w + (size_t)l * 768 * 768,
            fc1_w + (size_t)l * 768 * 3072, fc2_w + (size_t)l * 3072 * 768, whi, wlo);
        ln_tok<<<dim3(MTOT), blk, 0, stream>>>(cur, xn, ln1_w + l * 768, ln1_b + l * 768, nTokP);
        mfma_gemm<0, 0><<<dim3(gm, 18), blk, 0, stream>>>(
            xn, 768, whi + WOFF_QKV, wlo + WOFF_QKV, qkv_b + (size_t)l * 2304,
            nullptr, qkvb, 2304, 768, MTOT, nTokP);
        attn_v2<<<dim3(BB * NHEAD, 7), blk, 0, stream>>>(qkvb, attnout, jac, nTokP);
        mfma_gemm<0, 1><<<dim3(gm, 6), blk, 0, stream>>>(
            attnout, 768, whi + WOFF_PROJ, wlo + WOFF_PROJ, proj_b + (size_t)l * 768,
            cur, cur, 768, 768, MTOT, nTokP);
        ln_tok<<<dim3(MTOT), blk, 0, stream>>>(cur, xn, ln2_w + l * 768, ln2_b + l * 768, nTokP);
        mfma_gemm<0, 2><<<dim3(gm, 24), blk, 0, stream>>>(
            xn, 768, whi + WOFF_FC1, wlo + WOFF_FC1, fc1_b + (size_t)l * 3072,
            nullptr, hbuf, 3072, 768, MTOT, nTokP);
        mfma_gemm<0, 1><<<dim3(gm, 6), blk, 0, stream>>>(
            hbuf, 3072, whi + WOFF_FC2, wlo + WOFF_FC2, fc2_b + (size_t)l * 768,
            cur, cur, 768, 3072, MTOT, nTokP);
        decide_kernel<<<dim3(1), blk, 0, stream>>>(jac, nTokP, nTokNextP, keepIdx,
                                                   prevMass, prevValidP);
        gather_kernel<<<dim3(MTOT), dim3(192), 0, stream>>>(cur, nxt, keepIdx, nTokNextP, nTokP);
    }
    ln_cls<<<dim3(BB), blk, 0, stream>>>(bufs[0], lnC, norm_w, norm_b);
    head_kernel<<<dim3(BB, 4), blk, 0, stream>>>(lnC, head_w, head_b, out);
}

// Round 3
// 7431.989 us; speedup vs baseline: 3.5041x; 1.3080x over previous
//
#include <hip/hip_runtime.h>
#include <math.h>

#define DEV_INLINE __device__ __forceinline__

constexpr int BB     = 32;
constexpr int DMODEL = 768;
constexpr int NHEAD  = 12;
constexpr int NPATCH = 196;
constexpr int NTOK   = 197;
constexpr int NLAYER = 12;
constexpr int NCLASS = 1000;
constexpr int MTOT   = BB * NTOK;   // 6304

typedef __attribute__((ext_vector_type(4))) float f32x4;
typedef __attribute__((ext_vector_type(8))) short bf16x8;

// fp32 -> (hi, lo) bf16 pair, both RNE. x ~= hi + lo with ~17 mantissa bits.
DEV_INLINE void split2(float x, unsigned short& hi, unsigned short& lo) {
    unsigned u = __builtin_bit_cast(unsigned, x);
    unsigned r = (u + 0x7FFFu + ((u >> 16) & 1u)) >> 16;
    hi = (unsigned short)r;
    float fh = __builtin_bit_cast(float, r << 16);
    float l = x - fh;
    unsigned ul = __builtin_bit_cast(unsigned, l);
    lo = (unsigned short)((ul + 0x7FFFu + ((ul >> 16) & 1u)) >> 16);
}

DEV_INLINE unsigned split_pack(float x) {
    unsigned short h, l; split2(x, h, l);
    return (unsigned)h | ((unsigned)l << 16);
}

// async 16B global -> LDS (wave-uniform LDS base + lane*16)
DEV_INLINE void gload16(const unsigned short* g, unsigned short* l) {
    __builtin_amdgcn_global_load_lds(
        (const __attribute__((address_space(1))) unsigned int*)g,
        (__attribute__((address_space(3))) unsigned int*)l, 16, 0, 0);
}

DEV_INLINE float block_reduce_sum(float v, float* sbuf) {
    #pragma unroll
    for (int off = 32; off > 0; off >>= 1) v += __shfl_down(v, off, 64);
    int lane = threadIdx.x & 63, w = threadIdx.x >> 6;
    __syncthreads();
    if (lane == 0) sbuf[w] = v;
    __syncthreads();
    return sbuf[0] + sbuf[1] + sbuf[2] + sbuf[3];
}

// ---------------------------------------------------------------- state init
__global__ void state_init(int* nTokPtr, int* prevValidPtr) {
    *nTokPtr = NTOK;
    *prevValidPtr = 0;
}

// ---------------------------------------------------------------- CLS row
__global__ __launch_bounds__(256)
void cls_init(const float* __restrict__ cls, const float* __restrict__ pos,
              float* __restrict__ tok) {
    int b = blockIdx.x;
    for (int i = threadIdx.x; i < DMODEL; i += 256)
        tok[(size_t)b * NTOK * DMODEL + i] = cls[i] + pos[i];
}

// ------------------------------------------------- patch weight convert (tiled)
// patch_w is [N=768][K=768] row-major; write swizzled 8KB tiles [npanel][kb]
__global__ __launch_bounds__(256)
void wconv_patch(const float* __restrict__ src, unsigned short* __restrict__ hi,
                 unsigned short* __restrict__ lo) {
    int id = blockIdx.x * 256 + threadIdx.x;   // (n, k-chunk8): 768*96
    if (id >= 768 * 96) return;
    int n = id / 96, ch = id % 96;
    int k = ch * 8;
    float4 a = *(const float4*)(src + (size_t)n * 768 + k);
    float4 b = *(const float4*)(src + (size_t)n * 768 + k + 4);
    unsigned short h[8], l[8];
    split2(a.x,h[0],l[0]); split2(a.y,h[1],l[1]); split2(a.z,h[2],l[2]); split2(a.w,h[3],l[3]);
    split2(b.x,h[4],l[4]); split2(b.y,h[5],l[5]); split2(b.z,h[6],l[6]); split2(b.w,h[7],l[7]);
    int npanel = n >> 7, c = n & 127;
    int kbi = k >> 5, chunk = (k >> 3) & 3;
    size_t base = ((size_t)npanel * 24 + kbi) * 4096
                + c * 32 + ((chunk ^ ((c >> 1) & 3)) << 3);
    bf16x8 hv, lv;
    #pragma unroll
    for (int j = 0; j < 8; ++j) { hv[j] = (short)h[j]; lv[j] = (short)l[j]; }
    *(bf16x8*)(hi + base) = hv;
    *(bf16x8*)(lo + base) = lv;
}

// ------------------------------------------------- per-layer weight convert
constexpr size_t WOFF_QKV  = 0;
constexpr size_t WOFF_PROJ = (size_t)768 * 2304;
constexpr size_t WOFF_FC1  = WOFF_PROJ + (size_t)768 * 768;
constexpr size_t WOFF_FC2  = WOFF_FC1 + (size_t)768 * 3072;
constexpr size_t WTOTAL    = WOFF_FC2 + (size_t)3072 * 768;   // 7,077,888

// transpose [K][N] fp32 -> swizzled tiles [npanel][kb][4096], hi/lo planes
__global__ __launch_bounds__(256)
void wconv_layer(const float* __restrict__ qkvw, const float* __restrict__ projw,
                 const float* __restrict__ fc1w, const float* __restrict__ fc2w,
                 unsigned short* __restrict__ hi, unsigned short* __restrict__ lo) {
    __shared__ float tile[32][33];
    int bid = blockIdx.x;
    const float* src; int Kd, Nd; size_t dofs;
    if (bid < 1728)      { src = qkvw;  Kd = 768;  Nd = 2304; dofs = WOFF_QKV; }
    else if (bid < 2304) { bid -= 1728; src = projw; Kd = 768;  Nd = 768;  dofs = WOFF_PROJ; }
    else if (bid < 4608) { bid -= 2304; src = fc1w;  Kd = 768;  Nd = 3072; dofs = WOFF_FC1; }
    else                 { bid -= 4608; src = fc2w;  Kd = 3072; Nd = 768;  dofs = WOFF_FC2; }
    const int nkb = Kd >> 5;
    int ntx = Nd / 32;
    int n0 = (bid % ntx) * 32, k0 = (bid / ntx) * 32;
    int tx = threadIdx.x & 31, ty = threadIdx.x >> 5;   // 32 x 8
    #pragma unroll
    for (int i = 0; i < 32; i += 8)
        tile[ty + i][tx] = src[(size_t)(k0 + ty + i) * Nd + n0 + tx];   // [k][n]
    __syncthreads();
    int t = threadIdx.x;
    if (t < 128) {
        int nl = t >> 2, chunk = t & 3;
        unsigned short h[8], l[8];
        #pragma unroll
        for (int j = 0; j < 8; ++j) split2(tile[chunk * 8 + j][nl], h[j], l[j]);
        int n = n0 + nl, k = k0 + chunk * 8;
        int npanel = n >> 7, c = n & 127;
        int kbi = k >> 5;
        size_t base = dofs + ((size_t)npanel * nkb + kbi) * 4096
                    + c * 32 + ((chunk ^ ((c >> 1) & 3)) << 3);
        bf16x8 hv, lv;
        #pragma unroll
        for (int j = 0; j < 8; ++j) { hv[j] = (short)h[j]; lv[j] = (short)l[j]; }
        *(bf16x8*)(hi + base) = hv;
        *(bf16x8*)(lo + base) = lv;
    }
}

// ------------------------------------------------------------- MFMA GEMM
// ASRC: 0 = packed hi|lo<<16 uint activations [m][lda]; 1 = fp32 im2col of x
// EPI : 0 = +bias (fp32 C); 1 = +bias+resid (fp32 C); 2 = +bias,GELU (packed C);
//       3 = patch (+bias+pos, fp32 scatter into tok rows 1..196)
template<int ASRC, int EPI>
__global__ __launch_bounds__(256)
void mfma_gemm(const void* __restrict__ A, int lda,
               const unsigned short* __restrict__ Wht,
               const unsigned short* __restrict__ Wlt,
               const float* __restrict__ bias,
               const float* __restrict__ resid,
               void* __restrict__ C, int ldc,
               int K, int Mtot, int gm, int gn,
               const int* __restrict__ nTokPtr) {
    const int nTok = (ASRC == 0) ? *nTokPtr : NTOK;
    // bijective XCD-chunk swizzle (m204): XCD owns contiguous m-slab, n inner
    int nb = gm * gn;
    int o = blockIdx.x;
    int q8 = nb >> 3, r8 = nb & 7;
    int xcd = o & 7, wi = o >> 3;
    int fin = (xcd < r8 ? xcd * (q8 + 1) : r8 * (q8 + 1) + (xcd - r8) * q8) + wi;
    int bm = fin / gn, bn = fin - bm * gn;
    const int m0 = bm * 128, n0 = bn * 128;
    if (m0 >= Mtot) return;
    if (ASRC == 0) {
        int ts = m0 % NTOK;
        if (!(ts < nTok || ts + 128 > NTOK)) return;   // whole tile pruned
    }
    __shared__ unsigned short Ah[4096], Al[4096], Bh[4096], Bl[4096];
    const int tid = threadIdx.x;
    const int lane = tid & 63, wid = tid >> 6;
    const int wm = wid >> 1, wn = wid & 1;
    const int fr = lane & 15, fg = lane >> 4;

    f32x4 acc[4][4];
    #pragma unroll
    for (int i = 0; i < 4; ++i)
        #pragma unroll
        for (int j = 0; j < 4; ++j) acc[i][j] = (f32x4){0.f, 0.f, 0.f, 0.f};

    // A staging: thread covers row tid>>1, chunks (tid&1)*2, +1  (16 elems)
    const int arow = tid >> 1;
    const int acp  = (tid & 1) * 2;
    const int am = m0 + arow;
    bool aval = am < Mtot;
    if (ASRC == 0) aval = aval && (am % NTOK) < nTok;
    size_t abase;
    if (ASRC == 0) abase = (size_t)am * lda;
    else {
        int b = am / NPATCH, pp = am - b * NPATCH;
        int py = pp / 14, px = pp - py * 14;
        abase = (size_t)b * (3 * 224 * 224) + (size_t)(py * 16) * 224 + px * 16;
    }
    const int axor = (arow >> 1) & 3;
    const int aoff0 = arow * 32 + ((acp ^ axor) << 3);
    const int aoff1 = arow * 32 + (((acp + 1) ^ axor) << 3);
    const int nkb = K >> 5;
    const int wbase = wid * 512;        // shorts
    const int g8 = tid * 8;             // shorts

    for (int kbi = 0; kbi < nkb; ++kbi) {
        const int kb = kbi << 5;
        // ---- B: async global->LDS from pre-swizzled tiles (linear copy)
        {
            size_t tb = ((size_t)bn * nkb + kbi) * 4096;
            gload16(Wht + tb + g8,        &Bh[wbase]);
            gload16(Wht + tb + g8 + 2048, &Bh[wbase + 2048]);
            gload16(Wlt + tb + g8,        &Bl[wbase]);
            gload16(Wlt + tb + g8 + 2048, &Bl[wbase + 2048]);
        }
        // ---- A: reg staging
        unsigned ph[8], pl[8];
        if (ASRC == 0) {
            unsigned u[16] = {0,0,0,0,0,0,0,0,0,0,0,0,0,0,0,0};
            if (aval) {
                const unsigned* ap = (const unsigned*)A + abase + kb + acp * 8;
                *(uint4*)&u[0]  = *(const uint4*)ap;
                *(uint4*)&u[4]  = *(const uint4*)(ap + 4);
                *(uint4*)&u[8]  = *(const uint4*)(ap + 8);
                *(uint4*)&u[12] = *(const uint4*)(ap + 12);
            }
            #pragma unroll
            for (int j = 0; j < 8; ++j) {
                unsigned a = u[2 * j], b = u[2 * j + 1];
                ph[j] = (a & 0xffffu) | (b << 16);
                pl[j] = (a >> 16) | (b & 0xffff0000u);
            }
        } else {
            float f[16] = {0,0,0,0,0,0,0,0,0,0,0,0,0,0,0,0};
            if (aval) {
                int k = kb + acp * 8;
                size_t off = abase + (size_t)(k >> 8) * (224 * 224)
                           + (size_t)((k >> 4) & 15) * 224;
                *(float4*)&f[0]  = *(const float4*)((const float*)A + off);
                *(float4*)&f[4]  = *(const float4*)((const float*)A + off + 4);
                *(float4*)&f[8]  = *(const float4*)((const float*)A + off + 8);
                *(float4*)&f[12] = *(const float4*)((const float*)A + off + 12);
            }
            #pragma unroll
            for (int j = 0; j < 8; ++j) {
                unsigned short h0, l0, h1, l1;
                split2(f[2 * j], h0, l0); split2(f[2 * j + 1], h1, l1);
                ph[j] = (unsigned)h0 | ((unsigned)h1 << 16);
                pl[j] = (unsigned)l0 | ((unsigned)l1 << 16);
            }
        }
        *(uint4*)&Ah[aoff0] = *(uint4*)&ph[0];
        *(uint4*)&Ah[aoff1] = *(uint4*)&ph[4];
        *(uint4*)&Al[aoff0] = *(uint4*)&pl[0];
        *(uint4*)&Al[aoff1] = *(uint4*)&pl[4];
        __syncthreads();
        // ---- fragments + 48 MFMAs
        bf16x8 ah[4], al4[4], bh4[4], bl4[4];
        #pragma unroll
        for (int i = 0; i < 4; ++i) {
            int row = wm * 64 + i * 16 + fr;
            int aoff = row * 32 + ((fg ^ ((row >> 1) & 3)) << 3);
            ah[i]  = *(const bf16x8*)&Ah[aoff];
            al4[i] = *(const bf16x8*)&Al[aoff];
            int col = wn * 64 + i * 16 + fr;
            int boff = col * 32 + ((fg ^ ((col >> 1) & 3)) << 3);
            bh4[i] = *(const bf16x8*)&Bh[boff];
            bl4[i] = *(const bf16x8*)&Bl[boff];
        }
        #pragma unroll
        for (int i = 0; i < 4; ++i)
            #pragma unroll
            for (int j = 0; j < 4; ++j) {
                acc[i][j] = __builtin_amdgcn_mfma_f32_16x16x32_bf16(ah[i],  bh4[j], acc[i][j], 0, 0, 0);
                acc[i][j] = __builtin_amdgcn_mfma_f32_16x16x32_bf16(ah[i],  bl4[j], acc[i][j], 0, 0, 0);
                acc[i][j] = __builtin_amdgcn_mfma_f32_16x16x32_bf16(al4[i], bh4[j], acc[i][j], 0, 0, 0);
            }
        __syncthreads();
    }
    // ---- epilogue (C/D layout: col = lane&15, row = (lane>>4)*4 + e)
    #pragma unroll
    for (int i = 0; i < 4; ++i) {
        #pragma unroll
        for (int j = 0; j < 4; ++j) {
            #pragma unroll
            for (int e = 0; e < 4; ++e) {
                int m = m0 + wm * 64 + i * 16 + fg * 4 + e;
                int n = n0 + wn * 64 + j * 16 + fr;
                if (m >= Mtot) continue;
                if (ASRC == 0 && (m % NTOK) >= nTok) continue;
                float v = acc[i][j][e] + bias[n];
                if constexpr (EPI == 0) {
                    ((float*)C)[(size_t)m * ldc + n] = v;
                } else if constexpr (EPI == 1) {
                    ((float*)C)[(size_t)m * ldc + n] = v + resid[(size_t)m * ldc + n];
                } else if constexpr (EPI == 2) {
                    v = 0.5f * v * (1.0f + erff(v * 0.70710678118654752f));
                    ((unsigned*)C)[(size_t)m * ldc + n] = split_pack(v);
                } else {
                    int b = m / NPATCH, pp = m - b * NPATCH;
                    v += resid[(size_t)(1 + pp) * DMODEL + n];   // pos embed
                    ((float*)C)[((size_t)b * NTOK + 1 + pp) * DMODEL + n] = v;
                }
            }
        }
    }
}

// ---------------------------------------------------------------- LayerNorm
__global__ __launch_bounds__(256)
void ln_tok(const float* __restrict__ X, unsigned* __restrict__ Y,
            const float* __restrict__ w, const float* __restrict__ b,
            const int* __restrict__ nTokPtr) {
    int m = blockIdx.x;
    if ((m % NTOK) >= *nTokPtr) return;
    __shared__ float sbuf[4];
    const float* x = X + (size_t)m * DMODEL;
    int tid = threadIdx.x;
    float v[3];
    #pragma unroll
    for (int i = 0; i < 3; i++) v[i] = x[tid + i * 256];
    float mu = block_reduce_sum(v[0] + v[1] + v[2], sbuf) * (1.0f / 768.0f);
    float d2 = 0.f;
    #pragma unroll
    for (int i = 0; i < 3; i++) { float d = v[i] - mu; d2 = fmaf(d, d, d2); }
    float var = block_reduce_sum(d2, sbuf) * (1.0f / 768.0f);
    float rstd = rsqrtf(var + 1e-6f);
    #pragma unroll
    for (int i = 0; i < 3; i++) {
        int idx = tid + i * 256;
        float y = (v[i] - mu) * rstd * w[idx] + b[idx];
        Y[(size_t)m * DMODEL + idx] = split_pack(y);
    }
}

__global__ __launch_bounds__(256)
void ln_cls(const float* __restrict__ X, float* __restrict__ Y,
            const float* __restrict__ w, const float* __restrict__ b) {
    int bb = blockIdx.x;
    __shared__ float sbuf[4];
    const float* x = X + (size_t)bb * NTOK * DMODEL;
    int tid = threadIdx.x;
    float v[3];
    #pragma unroll
    for (int i = 0; i < 3; i++) v[i] = x[tid + i * 256];
    float mu = block_reduce_sum(v[0] + v[1] + v[2], sbuf) * (1.0f / 768.0f);
    float d2 = 0.f;
    #pragma unroll
    for (int i = 0; i < 3; i++) { float d = v[i] - mu; d2 = fmaf(d, d, d2); }
    float var = block_reduce_sum(d2, sbuf) * (1.0f / 768.0f);
    float rstd = rsqrtf(var + 1e-6f);
    #pragma unroll
    for (int i = 0; i < 3; i++) {
        int idx = tid + i * 256;
        Y[(size_t)bb * DMODEL + idx] = (v[i] - mu) * rstd * w[idx] + b[idx];
    }
}

// ---------------------------------------------------------------- attention
// flash-style: grid (b*h, 7 q-tiles of 32). Writes packed hi/lo bf16 out.
__global__ __launch_bounds__(256)
void attn_v2(const float* __restrict__ qkv, unsigned* __restrict__ outu,
             float* __restrict__ jacg, const int* __restrict__ nTokPtr) {
    const int nTok = *nTokPtr;
    const int bh = blockIdx.x;
    const int b = bh / NHEAD, h = bh % NHEAD;
    const int q0 = blockIdx.y * 32;
    if (q0 >= nTok) return;
    __shared__ float Qs[32][68];
    __shared__ float KVs[64][68];
    __shared__ float Ss[32][67];
    __shared__ float mrow[32], lrow[32], frow[32];
    __shared__ float s0row[208];
    __shared__ float vnrow[208];
    const int tid = threadIdx.x;
    const float* base = qkv + (size_t)b * NTOK * 2304 + (size_t)h * 64;

    {
        int r = tid >> 3, fc = tid & 7;
        int q = q0 + r;
        #pragma unroll
        for (int p = 0; p < 2; ++p) {
            float4 v = make_float4(0.f, 0.f, 0.f, 0.f);
            if (q < nTok) v = *(const float4*)(base + (size_t)q * 2304 + (fc + p * 8) * 4);
            *(float4*)&Qs[r][(fc + p * 8) * 4] = v;
        }
    }
    if (tid < 32) { mrow[tid] = -INFINITY; lrow[tid] = 0.f; }

    float o[2][4] = {{0.f,0.f,0.f,0.f},{0.f,0.f,0.f,0.f}};
    const int qq = tid & 15, dd = tid >> 4;
    const int q2 = qq * 2;
    const int njt = (nTok + 63) >> 6;

    for (int jt = 0; jt < njt; ++jt) {
        const int jb = jt * 64;
        __syncthreads();
        {   // stage K
            int jr = tid >> 2, fc = tid & 3;
            int j = jb + jr;
            const float* krow = base + (size_t)j * 2304 + 768;
            #pragma unroll
            for (int p = 0; p < 4; ++p) {
                float4 v = make_float4(0.f, 0.f, 0.f, 0.f);
                if (j < nTok) v = *(const float4*)(krow + (fc + p * 4) * 4);
                *(float4*)&KVs[jr][(fc + p * 4) * 4] = v;
            }
        }
        __syncthreads();
        {   // QK^T
            const int jj = tid >> 4;
            float sacc[2][4] = {{0,0,0,0},{0,0,0,0}};
            #pragma unroll 4
            for (int d0 = 0; d0 < 16; ++d0) {
                float4 qa = *(const float4*)&Qs[q2][d0 * 4];
                float4 qb = *(const float4*)&Qs[q2 + 1][d0 * 4];
                #pragma unroll
                for (int r = 0; r < 4; ++r) {
                    float4 kv = *(const float4*)&KVs[jj * 4 + r][d0 * 4];
                    sacc[0][r] = fmaf(qa.x, kv.x, sacc[0][r]);
                    sacc[0][r] = fmaf(qa.y, kv.y, sacc[0][r]);
                    sacc[0][r] = fmaf(qa.z, kv.z, sacc[0][r]);
                    sacc[0][r] = fmaf(qa.w, kv.w, sacc[0][r]);
                    sacc[1][r] = fmaf(qb.x, kv.x, sacc[1][r]);
                    sacc[1][r] = fmaf(qb.y, kv.y, sacc[1][r]);
                    sacc[1][r] = fmaf(qb.z, kv.z, sacc[1][r]);
                    sacc[1][r] = fmaf(qb.w, kv.w, sacc[1][r]);
                }
            }
            #pragma unroll
            for (int s = 0; s < 2; ++s) {
                int q = q0 + q2 + s;
                #pragma unroll
                for (int r = 0; r < 4; ++r) {
                    int j = jb + jj * 4 + r;
                    float sv = (j < nTok && q < nTok) ? sacc[s][r] * 0.125f : -INFINITY;
                    Ss[q2 + s][jj * 4 + r] = sv;
                    if (q0 == 0 && qq == 0 && s == 0 && j < nTok) s0row[j] = sv;
                }
            }
        }
        __syncthreads();
        if (tid < 32) {   // online softmax
            int q = q0 + tid;
            if (q < nTok) {
                int jn = min(64, nTok - jb);
                float mt = -INFINITY;
                for (int j = 0; j < jn; ++j) mt = fmaxf(mt, Ss[tid][j]);
                float mnew = fmaxf(mrow[tid], mt);
                float f = expf(mrow[tid] - mnew);
                float sum = 0.f;
                for (int j = 0; j < jn; ++j) {
                    float p = expf(Ss[tid][j] - mnew);
                    Ss[tid][j] = p; sum += p;
                }
                for (int j = jn; j < 64; ++j) Ss[tid][j] = 0.f;
                lrow[tid] = lrow[tid] * f + sum;
                mrow[tid] = mnew;
                frow[tid] = f;
            }
        }
        {   // stage V (overwrites K)
            int jr = tid >> 2, fc = tid & 3;
            int j = jb + jr;
            const float* vrow = base + (size_t)j * 2304 + 1536;
            #pragma unroll
            for (int p = 0; p < 4; ++p) {
                float4 v = make_float4(0.f, 0.f, 0.f, 0.f);
                if (j < nTok) v = *(const float4*)(vrow + (fc + p * 4) * 4);
                *(float4*)&KVs[jr][(fc + p * 4) * 4] = v;
            }
        }
        __syncthreads();
        if (q0 == 0 && tid < 64) {
            int j = jb + tid;
            if (j < nTok) {
                float s = 0.f;
                for (int d = 0; d < 64; ++d) { float v = KVs[tid][d]; s = fmaf(v, v, s); }
                vnrow[j] = sqrtf(s);
            }
        }
        {   // PV accumulate
            float f0 = frow[q2], f1 = frow[q2 + 1];
            #pragma unroll
            for (int r = 0; r < 4; ++r) { o[0][r] *= f0; o[1][r] *= f1; }
            for (int j = 0; j < 64; ++j) {
                float p0 = Ss[q2][j], p1 = Ss[q2 + 1][j];
                float4 vv = *(const float4*)&KVs[j][dd * 4];
                o[0][0] = fmaf(p0, vv.x, o[0][0]);
                o[0][1] = fmaf(p0, vv.y, o[0][1]);
                o[0][2] = fmaf(p0, vv.z, o[0][2]);
                o[0][3] = fmaf(p0, vv.w, o[0][3]);
                o[1][0] = fmaf(p1, vv.x, o[1][0]);
                o[1][1] = fmaf(p1, vv.y, o[1][1]);
                o[1][2] = fmaf(p1, vv.z, o[1][2]);
                o[1][3] = fmaf(p1, vv.w, o[1][3]);
            }
        }
    }
    __syncthreads();
    #pragma unroll
    for (int s = 0; s < 2; ++s) {
        int q = q0 + q2 + s;
        if (q < nTok) {
            float inv = 1.0f / lrow[q2 + s];
            uint4 pv;
            pv.x = split_pack(o[s][0] * inv);
            pv.y = split_pack(o[s][1] * inv);
            pv.z = split_pack(o[s][2] * inv);
            pv.w = split_pack(o[s][3] * inv);
            *(uint4*)(outu + ((size_t)b * NTOK + q) * DMODEL + (size_t)h * 64 + dd * 4) = pv;
        }
    }
    if (q0 == 0) {
        float m0f = mrow[0], l0 = lrow[0];
        for (int j = 1 + tid; j < nTok; j += 256)
            jacg[(size_t)bh * NPATCH + (j - 1)] = (expf(s0row[j] - m0f) / l0) * vnrow[j];
    }
}

// ------------------------------------------------------- prune decision
__global__ __launch_bounds__(256)
void decide_kernel(const float* __restrict__ jac,
                   int* __restrict__ nTokPtr, int* __restrict__ nTokNextPtr,
                   int* __restrict__ keepIdx, float* __restrict__ prevMassPtr,
                   int* __restrict__ prevValidPtr) {
    const int nTok = *nTokPtr;
    const int N = nTok - 1;
    const int tid = threadIdx.x;
    if (N <= 16) {
        if (tid == 0) { *prevValidPtr = 0; *nTokNextPtr = nTok; }
        for (int t = tid; t < nTok; t += 256) keepIdx[t] = t;
        return;
    }
    __shared__ float impF[NPATCH];
    __shared__ int   sel[NPATCH];
    __shared__ int   s_next;
    for (int j = tid; j < N; j += 256) {
        double s = 0.0;
        for (int r = 0; r < BB * NHEAD; r++) s += (double)jac[(size_t)r * NPATCH + j];
        impF[j] = (float)(s * (1.0 / 384.0));
    }
    __syncthreads();
    if (tid == 0) {
        double ms = 0.0;
        for (int j = 0; j < N; j++) ms += (double)impF[j];
        float massF = (float)ms;
        float meanF = (float)(ms / (double)N);
        double vs = 0.0;
        for (int j = 0; j < N; j++) { double d = (double)impF[j] - (double)meanF; vs += d * d; }
        float stdF = (float)sqrt(vs / (double)N);
        float rho = stdF / (meanF + 1e-6f);
        int nnext;
        if (*prevValidPtr != 0) {
            float pm = *prevMassPtr;
            float drift = fabsf(massF - pm) / (pm + 1e-6f);
            float kr = 1.0f - 0.01f * rho * (1.0f + drift);
            kr = fminf(fmaxf(kr, 0.0f), 1.0f);
            int t = (int)((double)N * (double)kr);
            nnext = t < 16 ? 16 : t;
        } else {
            nnext = N;
        }
        *prevMassPtr = massF;
        *prevValidPtr = 1;
        s_next = nnext;
        *nTokNextPtr = nnext + 1;
    }
    __syncthreads();
    int nnext = s_next;
    if (nnext < N) {
        for (int j = tid; j < N; j += 256) {
            float vj = impF[j];
            int rank = 0;
            for (int i = 0; i < N; i++) {
                float vi = impF[i];
                rank += (vi > vj || (vi == vj && i < j)) ? 1 : 0;
            }
            sel[j] = (rank < nnext) ? 1 : 0;
        }
        __syncthreads();
        if (tid == 0) {
            int c = 1;
            keepIdx[0] = 0;
            for (int j = 0; j < N; j++) if (sel[j]) keepIdx[c++] = j + 1;
        }
    } else {
        for (int t = tid; t < nTok; t += 256) keepIdx[t] = t;
    }
}

// ---------------------------------------------------------------- gather
__global__ __launch_bounds__(192)
void gather_kernel(const float* __restrict__ src, float* __restrict__ dst,
                   const int* __restrict__ keepIdx,
                   const int* __restrict__ nTokNextPtr, int* __restrict__ nTokPtr) {
    int nn = *nTokNextPtr;
    int m = blockIdx.x;
    int b = m / NTOK, t = m - b * NTOK;
    if (t < nn) {
        int s = keepIdx[t];
        const float4* sp = (const float4*)(src + ((size_t)b * NTOK + s) * DMODEL);
        float4* dp = (float4*)(dst + ((size_t)b * NTOK + t) * DMODEL);
        dp[threadIdx.x] = sp[threadIdx.x];
    }
    if (m == 0 && threadIdx.x == 0) *nTokPtr = nn;
}

// ---------------------------------------------------------------- head
__global__ __launch_bounds__(256)
void head_kernel(const float* __restrict__ lnC, const float* __restrict__ W,
                 const float* __restrict__ hb, float* __restrict__ out) {
    int b = blockIdx.x;
    int n = blockIdx.y * 256 + threadIdx.x;
    __shared__ float xs[DMODEL];
    for (int i = threadIdx.x; i < DMODEL; i += 256) xs[i] = lnC[(size_t)b * DMODEL + i];
    __syncthreads();
    if (n < NCLASS) {
        float acc = hb[n];
        for (int d = 0; d < DMODEL; d++) acc = fmaf(xs[d], W[(size_t)d * NCLASS + n], acc);
        out[(size_t)b * NCLASS + n] = acc;
    }
}

// ================================================================= launch
extern "C" void kernel_launch(void* const* d_in, const int* in_sizes, int n_in,
                              void* d_out, int out_size, void* d_ws, size_t ws_size,
                              hipStream_t stream) {
    const float* x       = (const float*)d_in[0];
    const float* patch_w = (const float*)d_in[1];
    const float* patch_b = (const float*)d_in[2];
    const float* cls_tok = (const float*)d_in[3];
    const float* pos     = (const float*)d_in[4];
    const float* ln1_w   = (const float*)d_in[5];
    const float* ln1_b   = (const float*)d_in[6];
    const float* qkv_w   = (const float*)d_in[7];
    const float* qkv_b   = (const float*)d_in[8];
    const float* proj_w  = (const float*)d_in[9];
    const float* proj_b  = (const float*)d_in[10];
    const float* ln2_w   = (const float*)d_in[11];
    const float* ln2_b   = (const float*)d_in[12];
    const float* fc1_w   = (const float*)d_in[13];
    const float* fc1_b   = (const float*)d_in[14];
    const float* fc2_w   = (const float*)d_in[15];
    const float* fc2_b   = (const float*)d_in[16];
    const float* norm_w  = (const float*)d_in[17];
    const float* norm_b  = (const float*)d_in[18];
    const float* head_w  = (const float*)d_in[19];
    const float* head_b  = (const float*)d_in[20];
    float* out = (float*)d_out;

    char* ws = (char*)d_ws;
    size_t off = 0;
    auto alloc = [&](size_t nbytes) {
        char* p = ws + off;
        off += ((nbytes + 255) / 256) * 256;
        return p;
    };
    float* tokA = (float*)alloc((size_t)MTOT * DMODEL * 4);
    float* tokB = (float*)alloc((size_t)MTOT * DMODEL * 4);
    // union: qkvb (fp32, 58.1MB) | hbu (packed uint, 77.4MB) — disjoint lifetimes
    char* uni = alloc((size_t)MTOT * 3072 * 4);
    float* qkvb = (float*)uni;
    unsigned* hbu = (unsigned*)uni;
    unsigned* xnu  = (unsigned*)alloc((size_t)MTOT * DMODEL * 4);
    unsigned* outu = (unsigned*)alloc((size_t)MTOT * DMODEL * 4);
    unsigned short* whi = (unsigned short*)alloc(WTOTAL * 2);
    unsigned short* wlo = (unsigned short*)alloc(WTOTAL * 2);
    unsigned short* wphi = (unsigned short*)alloc((size_t)768 * 768 * 2);
    unsigned short* wplo = (unsigned short*)alloc((size_t)768 * 768 * 2);
    float* jac  = (float*)alloc((size_t)BB * NHEAD * NPATCH * 4);
    float* lnC  = (float*)alloc((size_t)BB * DMODEL * 4);
    float* prevMass = (float*)alloc(32);
    int* ints = (int*)alloc(1024);
    int* nTokP = ints; int* nTokNextP = ints + 1; int* prevValidP = ints + 2;
    int* keepIdx = ints + 4;

    dim3 blk(256);
    state_init<<<dim3(1), dim3(1), 0, stream>>>(nTokP, prevValidP);
    wconv_patch<<<dim3(288), blk, 0, stream>>>(patch_w, wphi, wplo);
    cls_init<<<dim3(BB), blk, 0, stream>>>(cls_tok, pos, tokA);
    mfma_gemm<1, 3><<<dim3(49 * 6), blk, 0, stream>>>(
        x, 0, wphi, wplo, patch_b, pos, tokA, DMODEL, 768, BB * NPATCH, 49, 6, nTokP);

    float* bufs[2] = {tokA, tokB};
    const int gm = (MTOT + 127) / 128;   // 50
    for (int l = 0; l < NLAYER; l++) {
        float* cur = bufs[l & 1];
        float* nxt = bufs[(l + 1) & 1];
        wconv_layer<<<dim3(6912), blk, 0, stream>>>(
            qkv_w + (size_t)l * 768 * 2304, proj_w + (size_t)l * 768 * 768,
            fc1_w + (size_t)l * 768 * 3072, fc2_w + (size_t)l * 3072 * 768, whi, wlo);
        ln_tok<<<dim3(MTOT), blk, 0, stream>>>(cur, xnu, ln1_w + l * 768, ln1_b + l * 768, nTokP);
        mfma_gemm<0, 0><<<dim3(gm * 18), blk, 0, stream>>>(
            xnu, 768, whi + WOFF_QKV, wlo + WOFF_QKV, qkv_b + (size_t)l * 2304,
            nullptr, qkvb, 2304, 768, MTOT, gm, 18, nTokP);
        attn_v2<<<dim3(BB * NHEAD, 7), blk, 0, stream>>>(qkvb, outu, jac, nTokP);
        mfma_gemm<0, 1><<<dim3(gm * 6), blk, 0, stream>>>(
            outu, 768, whi + WOFF_PROJ, wlo + WOFF_PROJ, proj_b + (size_t)l * 768,
            cur, cur, 768, 768, MTOT, gm, 6, nTokP);
        ln_tok<<<dim3(MTOT), blk, 0, stream>>>(cur, xnu, ln2_w + l * 768, ln2_b + l * 768, nTokP);
        mfma_gemm<0, 2><<<dim3(gm * 24), blk, 0, stream>>>(
            xnu, 768, whi + WOFF_FC1, wlo + WOFF_FC1, fc1_b + (size_t)l * 3072,
            nullptr, hbu, 3072, 768, MTOT, gm, 24, nTokP);
        mfma_gemm<0, 1><<<dim3(gm * 6), blk, 0, stream>>>(
            hbu, 3072, whi + WOFF_FC2, wlo + WOFF_FC2, fc2_b + (size_t)l * 768,
            cur, cur, 768, 3072, MTOT, gm, 6, nTokP);
        decide_kernel<<<dim3(1), blk, 0, stream>>>(jac, nTokP, nTokNextP, keepIdx,
                                                   prevMass, prevValidP);
        gather_kernel<<<dim3(MTOT), dim3(192), 0, stream>>>(cur, nxt, keepIdx, nTokNextP, nTokP);
    }
    ln_cls<<<dim3(BB), blk, 0, stream>>>(bufs[0], lnC, norm_w, norm_b);
    head_kernel<<<dim3(BB, 4), blk, 0, stream>>>(lnC, head_w, head_b, out);
}

// Round 4
// 6454.906 us; speedup vs baseline: 4.0345x; 1.1514x over previous
//
#include <hip/hip_runtime.h>
#include <math.h>

#define DEV_INLINE __device__ __forceinline__

constexpr int BB     = 32;
constexpr int DMODEL = 768;
constexpr int NHEAD  = 12;
constexpr int NPATCH = 196;
constexpr int NTOK   = 197;
constexpr int NLAYER = 12;
constexpr int NCLASS = 1000;
constexpr int MTOT   = BB * NTOK;   // 6304

typedef __attribute__((ext_vector_type(4))) float f32x4;
typedef __attribute__((ext_vector_type(8))) short bf16x8;

// fp32 -> (hi, lo) bf16 pair, both RNE. x ~= hi + lo with ~17 mantissa bits.
DEV_INLINE void split2(float x, unsigned short& hi, unsigned short& lo) {
    unsigned u = __builtin_bit_cast(unsigned, x);
    unsigned r = (u + 0x7FFFu + ((u >> 16) & 1u)) >> 16;
    hi = (unsigned short)r;
    float fh = __builtin_bit_cast(float, r << 16);
    float l = x - fh;
    unsigned ul = __builtin_bit_cast(unsigned, l);
    lo = (unsigned short)((ul + 0x7FFFu + ((ul >> 16) & 1u)) >> 16);
}

DEV_INLINE unsigned split_pack(float x) {
    unsigned short h, l; split2(x, h, l);
    return (unsigned)h | ((unsigned)l << 16);
}

// async 16B global -> LDS (wave-uniform LDS base + lane*16)
DEV_INLINE void gload16(const unsigned short* g, unsigned short* l) {
    __builtin_amdgcn_global_load_lds(
        (const __attribute__((address_space(1))) unsigned int*)g,
        (__attribute__((address_space(3))) unsigned int*)l, 16, 0, 0);
}

DEV_INLINE float block_reduce_sum(float v, float* sbuf) {
    #pragma unroll
    for (int off = 32; off > 0; off >>= 1) v += __shfl_down(v, off, 64);
    int lane = threadIdx.x & 63, w = threadIdx.x >> 6;
    __syncthreads();
    if (lane == 0) sbuf[w] = v;
    __syncthreads();
    return sbuf[0] + sbuf[1] + sbuf[2] + sbuf[3];
}

// ---------------------------------------------------------------- state init
__global__ void state_init(int* nTokPtr, int* prevValidPtr) {
    *nTokPtr = NTOK;
    *prevValidPtr = 0;
}

// ---------------------------------------------------------------- CLS row
__global__ __launch_bounds__(256)
void cls_init(const float* __restrict__ cls, const float* __restrict__ pos,
              float* __restrict__ tok) {
    int b = blockIdx.x;
    for (int i = threadIdx.x; i < DMODEL; i += 256)
        tok[(size_t)b * NTOK * DMODEL + i] = cls[i] + pos[i];
}

// ------------------------------------------------- patch weight convert (tiled)
__global__ __launch_bounds__(256)
void wconv_patch(const float* __restrict__ src, unsigned short* __restrict__ hi,
                 unsigned short* __restrict__ lo) {
    int id = blockIdx.x * 256 + threadIdx.x;   // (n, k-chunk8): 768*96
    if (id >= 768 * 96) return;
    int n = id / 96, ch = id % 96;
    int k = ch * 8;
    float4 a = *(const float4*)(src + (size_t)n * 768 + k);
    float4 b = *(const float4*)(src + (size_t)n * 768 + k + 4);
    unsigned short h[8], l[8];
    split2(a.x,h[0],l[0]); split2(a.y,h[1],l[1]); split2(a.z,h[2],l[2]); split2(a.w,h[3],l[3]);
    split2(b.x,h[4],l[4]); split2(b.y,h[5],l[5]); split2(b.z,h[6],l[6]); split2(b.w,h[7],l[7]);
    int npanel = n >> 7, c = n & 127;
    int kbi = k >> 5, chunk = (k >> 3) & 3;
    size_t base = ((size_t)npanel * 24 + kbi) * 4096
                + c * 32 + ((chunk ^ ((c >> 1) & 3)) << 3);
    bf16x8 hv, lv;
    #pragma unroll
    for (int j = 0; j < 8; ++j) { hv[j] = (short)h[j]; lv[j] = (short)l[j]; }
    *(bf16x8*)(hi + base) = hv;
    *(bf16x8*)(lo + base) = lv;
}

// ------------------------------------------------- per-layer weight convert
constexpr size_t WOFF_QKV  = 0;
constexpr size_t WOFF_PROJ = (size_t)768 * 2304;
constexpr size_t WOFF_FC1  = WOFF_PROJ + (size_t)768 * 768;
constexpr size_t WOFF_FC2  = WOFF_FC1 + (size_t)768 * 3072;
constexpr size_t WTOTAL    = WOFF_FC2 + (size_t)3072 * 768;   // 7,077,888

__global__ __launch_bounds__(256)
void wconv_layer(const float* __restrict__ qkvw, const float* __restrict__ projw,
                 const float* __restrict__ fc1w, const float* __restrict__ fc2w,
                 unsigned short* __restrict__ hi, unsigned short* __restrict__ lo) {
    __shared__ float tile[32][33];
    int bid = blockIdx.x;
    const float* src; int Kd, Nd; size_t dofs;
    if (bid < 1728)      { src = qkvw;  Kd = 768;  Nd = 2304; dofs = WOFF_QKV; }
    else if (bid < 2304) { bid -= 1728; src = projw; Kd = 768;  Nd = 768;  dofs = WOFF_PROJ; }
    else if (bid < 4608) { bid -= 2304; src = fc1w;  Kd = 768;  Nd = 3072; dofs = WOFF_FC1; }
    else                 { bid -= 4608; src = fc2w;  Kd = 3072; Nd = 768;  dofs = WOFF_FC2; }
    const int nkb = Kd >> 5;
    int ntx = Nd / 32;
    int n0 = (bid % ntx) * 32, k0 = (bid / ntx) * 32;
    int tx = threadIdx.x & 31, ty = threadIdx.x >> 5;   // 32 x 8
    #pragma unroll
    for (int i = 0; i < 32; i += 8)
        tile[ty + i][tx] = src[(size_t)(k0 + ty + i) * Nd + n0 + tx];   // [k][n]
    __syncthreads();
    int t = threadIdx.x;
    if (t < 128) {
        int nl = t >> 2, chunk = t & 3;
        unsigned short h[8], l[8];
        #pragma unroll
        for (int j = 0; j < 8; ++j) split2(tile[chunk * 8 + j][nl], h[j], l[j]);
        int n = n0 + nl, k = k0 + chunk * 8;
        int npanel = n >> 7, c = n & 127;
        int kbi = k >> 5;
        size_t base = dofs + ((size_t)npanel * nkb + kbi) * 4096
                    + c * 32 + ((chunk ^ ((c >> 1) & 3)) << 3);
        bf16x8 hv, lv;
        #pragma unroll
        for (int j = 0; j < 8; ++j) { hv[j] = (short)h[j]; lv[j] = (short)l[j]; }
        *(bf16x8*)(hi + base) = hv;
        *(bf16x8*)(lo + base) = lv;
    }
}

// ------------------------------------------------------------- MFMA GEMM
// ASRC: 0 = packed hi|lo<<16 uint activations [m][lda]; 1 = fp32 im2col of x
// EPI : 0 = +bias (PACKED C); 1 = +bias+resid (fp32 C); 2 = +bias,GELU (packed C);
//       3 = patch (+bias+pos, fp32 scatter into tok rows 1..196)
template<int ASRC, int EPI>
__global__ __launch_bounds__(256)
void mfma_gemm(const void* __restrict__ A, int lda,
               const unsigned short* __restrict__ Wht,
               const unsigned short* __restrict__ Wlt,
               const float* __restrict__ bias,
               const float* __restrict__ resid,
               void* __restrict__ C, int ldc,
               int K, int Mtot, int gm, int gn,
               const int* __restrict__ nTokPtr) {
    const int nTok = (ASRC == 0) ? *nTokPtr : NTOK;
    int nb = gm * gn;
    int o = blockIdx.x;
    int q8 = nb >> 3, r8 = nb & 7;
    int xcd = o & 7, wi = o >> 3;
    int fin = (xcd < r8 ? xcd * (q8 + 1) : r8 * (q8 + 1) + (xcd - r8) * q8) + wi;
    int bm = fin / gn, bn = fin - bm * gn;
    const int m0 = bm * 128, n0 = bn * 128;
    if (m0 >= Mtot) return;
    if (ASRC == 0) {
        int ts = m0 % NTOK;
        if (!(ts < nTok || ts + 128 > NTOK)) return;   // whole tile pruned
    }
    __shared__ unsigned short Ah[4096], Al[4096], Bh[4096], Bl[4096];
    const int tid = threadIdx.x;
    const int lane = tid & 63, wid = tid >> 6;
    const int wm = wid >> 1, wn = wid & 1;
    const int fr = lane & 15, fg = lane >> 4;

    f32x4 acc[4][4];
    #pragma unroll
    for (int i = 0; i < 4; ++i)
        #pragma unroll
        for (int j = 0; j < 4; ++j) acc[i][j] = (f32x4){0.f, 0.f, 0.f, 0.f};

    const int arow = tid >> 1;
    const int acp  = (tid & 1) * 2;
    const int am = m0 + arow;
    bool aval = am < Mtot;
    if (ASRC == 0) aval = aval && (am % NTOK) < nTok;
    size_t abase;
    if (ASRC == 0) abase = (size_t)am * lda;
    else {
        int b = am / NPATCH, pp = am - b * NPATCH;
        int py = pp / 14, px = pp - py * 14;
        abase = (size_t)b * (3 * 224 * 224) + (size_t)(py * 16) * 224 + px * 16;
    }
    const int axor = (arow >> 1) & 3;
    const int aoff0 = arow * 32 + ((acp ^ axor) << 3);
    const int aoff1 = arow * 32 + (((acp + 1) ^ axor) << 3);
    const int nkb = K >> 5;
    const int wbase = wid * 512;
    const int g8 = tid * 8;

    for (int kbi = 0; kbi < nkb; ++kbi) {
        const int kb = kbi << 5;
        {
            size_t tb = ((size_t)bn * nkb + kbi) * 4096;
            gload16(Wht + tb + g8,        &Bh[wbase]);
            gload16(Wht + tb + g8 + 2048, &Bh[wbase + 2048]);
            gload16(Wlt + tb + g8,        &Bl[wbase]);
            gload16(Wlt + tb + g8 + 2048, &Bl[wbase + 2048]);
        }
        unsigned ph[8], pl[8];
        if (ASRC == 0) {
            unsigned u[16] = {0,0,0,0,0,0,0,0,0,0,0,0,0,0,0,0};
            if (aval) {
                const unsigned* ap = (const unsigned*)A + abase + kb + acp * 8;
                *(uint4*)&u[0]  = *(const uint4*)ap;
                *(uint4*)&u[4]  = *(const uint4*)(ap + 4);
                *(uint4*)&u[8]  = *(const uint4*)(ap + 8);
                *(uint4*)&u[12] = *(const uint4*)(ap + 12);
            }
            #pragma unroll
            for (int j = 0; j < 8; ++j) {
                unsigned a = u[2 * j], b = u[2 * j + 1];
                ph[j] = (a & 0xffffu) | (b << 16);
                pl[j] = (a >> 16) | (b & 0xffff0000u);
            }
        } else {
            float f[16] = {0,0,0,0,0,0,0,0,0,0,0,0,0,0,0,0};
            if (aval) {
                int k = kb + acp * 8;
                size_t off = abase + (size_t)(k >> 8) * (224 * 224)
                           + (size_t)((k >> 4) & 15) * 224;
                *(float4*)&f[0]  = *(const float4*)((const float*)A + off);
                *(float4*)&f[4]  = *(const float4*)((const float*)A + off + 4);
                *(float4*)&f[8]  = *(const float4*)((const float*)A + off + 8);
                *(float4*)&f[12] = *(const float4*)((const float*)A + off + 12);
            }
            #pragma unroll
            for (int j = 0; j < 8; ++j) {
                unsigned short h0, l0, h1, l1;
                split2(f[2 * j], h0, l0); split2(f[2 * j + 1], h1, l1);
                ph[j] = (unsigned)h0 | ((unsigned)h1 << 16);
                pl[j] = (unsigned)l0 | ((unsigned)l1 << 16);
            }
        }
        *(uint4*)&Ah[aoff0] = *(uint4*)&ph[0];
        *(uint4*)&Ah[aoff1] = *(uint4*)&ph[4];
        *(uint4*)&Al[aoff0] = *(uint4*)&pl[0];
        *(uint4*)&Al[aoff1] = *(uint4*)&pl[4];
        __syncthreads();
        bf16x8 ah[4], al4[4], bh4[4], bl4[4];
        #pragma unroll
        for (int i = 0; i < 4; ++i) {
            int row = wm * 64 + i * 16 + fr;
            int aoff = row * 32 + ((fg ^ ((row >> 1) & 3)) << 3);
            ah[i]  = *(const bf16x8*)&Ah[aoff];
            al4[i] = *(const bf16x8*)&Al[aoff];
            int col = wn * 64 + i * 16 + fr;
            int boff = col * 32 + ((fg ^ ((col >> 1) & 3)) << 3);
            bh4[i] = *(const bf16x8*)&Bh[boff];
            bl4[i] = *(const bf16x8*)&Bl[boff];
        }
        #pragma unroll
        for (int i = 0; i < 4; ++i)
            #pragma unroll
            for (int j = 0; j < 4; ++j) {
                acc[i][j] = __builtin_amdgcn_mfma_f32_16x16x32_bf16(ah[i],  bh4[j], acc[i][j], 0, 0, 0);
                acc[i][j] = __builtin_amdgcn_mfma_f32_16x16x32_bf16(ah[i],  bl4[j], acc[i][j], 0, 0, 0);
                acc[i][j] = __builtin_amdgcn_mfma_f32_16x16x32_bf16(al4[i], bh4[j], acc[i][j], 0, 0, 0);
            }
        __syncthreads();
    }
    #pragma unroll
    for (int i = 0; i < 4; ++i) {
        #pragma unroll
        for (int j = 0; j < 4; ++j) {
            #pragma unroll
            for (int e = 0; e < 4; ++e) {
                int m = m0 + wm * 64 + i * 16 + fg * 4 + e;
                int n = n0 + wn * 64 + j * 16 + fr;
                if (m >= Mtot) continue;
                if (ASRC == 0 && (m % NTOK) >= nTok) continue;
                float v = acc[i][j][e] + bias[n];
                if constexpr (EPI == 0) {
                    ((unsigned*)C)[(size_t)m * ldc + n] = split_pack(v);
                } else if constexpr (EPI == 1) {
                    ((float*)C)[(size_t)m * ldc + n] = v + resid[(size_t)m * ldc + n];
                } else if constexpr (EPI == 2) {
                    v = 0.5f * v * (1.0f + erff(v * 0.70710678118654752f));
                    ((unsigned*)C)[(size_t)m * ldc + n] = split_pack(v);
                } else {
                    int b = m / NPATCH, pp = m - b * NPATCH;
                    v += resid[(size_t)(1 + pp) * DMODEL + n];   // pos embed
                    ((float*)C)[((size_t)b * NTOK + 1 + pp) * DMODEL + n] = v;
                }
            }
        }
    }
}

// ---------------------------------------------------------------- LayerNorm
__global__ __launch_bounds__(256)
void ln_tok(const float* __restrict__ X, unsigned* __restrict__ Y,
            const float* __restrict__ w, const float* __restrict__ b,
            const int* __restrict__ nTokPtr) {
    int m = blockIdx.x;
    if ((m % NTOK) >= *nTokPtr) return;
    __shared__ float sbuf[4];
    const float* x = X + (size_t)m * DMODEL;
    int tid = threadIdx.x;
    float v[3];
    #pragma unroll
    for (int i = 0; i < 3; i++) v[i] = x[tid + i * 256];
    float mu = block_reduce_sum(v[0] + v[1] + v[2], sbuf) * (1.0f / 768.0f);
    float d2 = 0.f;
    #pragma unroll
    for (int i = 0; i < 3; i++) { float d = v[i] - mu; d2 = fmaf(d, d, d2); }
    float var = block_reduce_sum(d2, sbuf) * (1.0f / 768.0f);
    float rstd = rsqrtf(var + 1e-6f);
    #pragma unroll
    for (int i = 0; i < 3; i++) {
        int idx = tid + i * 256;
        float y = (v[i] - mu) * rstd * w[idx] + b[idx];
        Y[(size_t)m * DMODEL + idx] = split_pack(y);
    }
}

__global__ __launch_bounds__(256)
void ln_cls(const float* __restrict__ X, float* __restrict__ Y,
            const float* __restrict__ w, const float* __restrict__ b) {
    int bb = blockIdx.x;
    __shared__ float sbuf[4];
    const float* x = X + (size_t)bb * NTOK * DMODEL;
    int tid = threadIdx.x;
    float v[3];
    #pragma unroll
    for (int i = 0; i < 3; i++) v[i] = x[tid + i * 256];
    float mu = block_reduce_sum(v[0] + v[1] + v[2], sbuf) * (1.0f / 768.0f);
    float d2 = 0.f;
    #pragma unroll
    for (int i = 0; i < 3; i++) { float d = v[i] - mu; d2 = fmaf(d, d, d2); }
    float var = block_reduce_sum(d2, sbuf) * (1.0f / 768.0f);
    float rstd = rsqrtf(var + 1e-6f);
    #pragma unroll
    for (int i = 0; i < 3; i++) {
        int idx = tid + i * 256;
        Y[(size_t)bb * DMODEL + idx] = (v[i] - mu) * rstd * w[idx] + b[idx];
    }
}

// ---------------------------------------------------------------- attention v3
// split-bf16 MFMA flash attention. qkv is PACKED (hi|lo<<16). grid (b*h, 7).
// Per block: 32 q-rows, j-tiles of 64. 4 waves: wave = (qh, xh).
__global__ __launch_bounds__(256)
void attn_v3(const unsigned* __restrict__ qkv, unsigned* __restrict__ outu,
             float* __restrict__ jacg, const int* __restrict__ nTokPtr) {
    const int nTok = *nTokPtr;
    const int bh = blockIdx.x;
    const int b = bh / NHEAD, h = bh % NHEAD;
    const int q0 = blockIdx.y * 32;
    if (q0 >= nTok) return;
    __shared__ unsigned short Kh[64 * 64], Kl[64 * 64];
    __shared__ unsigned short Vth[64 * 64], Vtl[64 * 64];
    __shared__ unsigned short Ph[32 * 64], Pl[32 * 64];
    __shared__ float Ss[32][68];
    __shared__ float mrow[32], lrow[32], frow[32];
    __shared__ float s0row[256], vnrow[256];
    __shared__ float vnpart[64][4];
    const int tid = threadIdx.x;
    const int lane = tid & 63, wv = tid >> 6;
    const int fr = lane & 15, fg = lane >> 4;
    const int qh = wv >> 1, xh = wv & 1;
    const unsigned* base = qkv + (size_t)b * NTOK * 2304 + (size_t)h * 64;

    {   // stage Q (packed) into Ss-as-uint
        unsigned* Qu = (unsigned*)&Ss[0][0];
        int r = tid >> 3, fc = tid & 7;
        int q = q0 + r;
        uint4 v = make_uint4(0,0,0,0), w = make_uint4(0,0,0,0);
        if (q < nTok) {
            v = *(const uint4*)(base + (size_t)q * 2304 + fc * 8);
            w = *(const uint4*)(base + (size_t)q * 2304 + fc * 8 + 4);
        }
        *(uint4*)&Qu[r * 68 + fc * 8] = v;
        *(uint4*)&Qu[r * 68 + fc * 8 + 4] = w;
    }
    if (tid < 32) { mrow[tid] = -INFINITY; lrow[tid] = 0.f; frow[tid] = 1.f; }
    __syncthreads();
    bf16x8 qah[2], qal[2];
    {   // extract Q fragments to regs (row = qh*16+fr, k = s*32+fg*8+i)
        const unsigned* Qu = (const unsigned*)&Ss[0][0];
        int r = qh * 16 + fr;
        #pragma unroll
        for (int s = 0; s < 2; ++s)
            #pragma unroll
            for (int i = 0; i < 8; ++i) {
                unsigned u = Qu[r * 68 + s * 32 + fg * 8 + i];
                qah[s][i] = (short)(u & 0xffffu);
                qal[s][i] = (short)(u >> 16);
            }
    }
    f32x4 oacc[2] = {{0,0,0,0},{0,0,0,0}};
    const int njt = (nTok + 63) >> 6;
    const int sj = tid & 63, sdh = tid >> 6;

    for (int jt = 0; jt < njt; ++jt) {
        const int jb = jt * 64;
        __syncthreads();   // prev PV / Q-extract done before overwrite
        {   // ---- stage K (swizzled rows) and V^T (scatter), both hi/lo bf16
            int j = jb + sj;
            uint4 ku[4], vu[4];
            if (j < nTok) {
                const unsigned* kr = base + (size_t)j * 2304 + 768 + sdh * 16;
                const unsigned* vr = base + (size_t)j * 2304 + 1536 + sdh * 16;
                ku[0] = *(const uint4*)kr;       ku[1] = *(const uint4*)(kr + 4);
                ku[2] = *(const uint4*)(kr + 8); ku[3] = *(const uint4*)(kr + 12);
                vu[0] = *(const uint4*)vr;       vu[1] = *(const uint4*)(vr + 4);
                vu[2] = *(const uint4*)(vr + 8); vu[3] = *(const uint4*)(vr + 12);
            } else {
                ku[0]=ku[1]=ku[2]=ku[3] = make_uint4(0,0,0,0);
                vu[0]=vu[1]=vu[2]=vu[3] = make_uint4(0,0,0,0);
            }
            const unsigned* kw = (const unsigned*)ku;
            bf16x8 kh0, kh1, kl0, kl1;
            #pragma unroll
            for (int i = 0; i < 8; ++i) {
                kh0[i] = (short)(kw[i] & 0xffffu);     kl0[i] = (short)(kw[i] >> 16);
                kh1[i] = (short)(kw[8 + i] & 0xffffu); kl1[i] = (short)(kw[8 + i] >> 16);
            }
            int c0 = sdh * 2;
            int ko0 = sj * 64 + ((c0 ^ (sj & 7)) << 3);
            int ko1 = sj * 64 + (((c0 + 1) ^ (sj & 7)) << 3);
            *(bf16x8*)&Kh[ko0] = kh0; *(bf16x8*)&Kh[ko1] = kh1;
            *(bf16x8*)&Kl[ko0] = kl0; *(bf16x8*)&Kl[ko1] = kl1;
            const unsigned* vw = (const unsigned*)vu;
            float pn = 0.f;
            #pragma unroll
            for (int i = 0; i < 16; ++i) {
                unsigned u = vw[i];
                int d = sdh * 16 + i;
                int si = d * 64 + (((sj >> 3) ^ (d & 7)) << 3) + (sj & 7);
                Vth[si] = (unsigned short)(u & 0xffffu);
                Vtl[si] = (unsigned short)(u >> 16);
                if (q0 == 0) {
                    float vf = __builtin_bit_cast(float, u << 16)
                             + __builtin_bit_cast(float, u & 0xffff0000u);
                    pn = fmaf(vf, vf, pn);
                }
            }
            if (q0 == 0) vnpart[sj][sdh] = pn;
        }
        __syncthreads();
        {   // ---- QK^T: wave (qh, xh) computes 16q x 32j
            f32x4 sacc[2] = {{0,0,0,0},{0,0,0,0}};
            #pragma unroll
            for (int s = 0; s < 2; ++s)
                #pragma unroll
                for (int t = 0; t < 2; ++t) {
                    int j = xh * 32 + t * 16 + fr;
                    int off = j * 64 + (((s * 4 + fg) ^ (j & 7)) << 3);
                    bf16x8 kbh = *(const bf16x8*)&Kh[off];
                    bf16x8 kbl = *(const bf16x8*)&Kl[off];
                    sacc[t] = __builtin_amdgcn_mfma_f32_16x16x32_bf16(qah[s], kbh, sacc[t], 0, 0, 0);
                    sacc[t] = __builtin_amdgcn_mfma_f32_16x16x32_bf16(qah[s], kbl, sacc[t], 0, 0, 0);
                    sacc[t] = __builtin_amdgcn_mfma_f32_16x16x32_bf16(qal[s], kbh, sacc[t], 0, 0, 0);
                }
            #pragma unroll
            for (int t = 0; t < 2; ++t)
                #pragma unroll
                for (int e = 0; e < 4; ++e) {
                    int q = q0 + qh * 16 + fg * 4 + e;
                    int j = jb + xh * 32 + t * 16 + fr;
                    Ss[qh * 16 + fg * 4 + e][xh * 32 + t * 16 + fr] =
                        (q < nTok && j < nTok) ? sacc[t][e] * 0.125f : -INFINITY;
                }
        }
        __syncthreads();
        {   // ---- wave-parallel online softmax (8 lanes/row)
            int q = tid >> 3, s = tid & 7;
            bool rowok = (q0 + q) < nTok;
            float4 va = *(const float4*)&Ss[q][s * 8];
            float4 vb = *(const float4*)&Ss[q][s * 8 + 4];
            if (q0 == 0 && q == 0) {
                *(float4*)&s0row[jb + s * 8] = va;
                *(float4*)&s0row[jb + s * 8 + 4] = vb;
            }
            float mx = fmaxf(fmaxf(fmaxf(va.x, va.y), fmaxf(va.z, va.w)),
                             fmaxf(fmaxf(vb.x, vb.y), fmaxf(vb.z, vb.w)));
            #pragma unroll
            for (int o = 1; o < 8; o <<= 1) mx = fmaxf(mx, __shfl_xor(mx, o));
            float mold = mrow[q];
            float mnew = fmaxf(mold, mx);
            float e[8];
            float sum = 0.f;
            if (rowok) {
                e[0] = expf(va.x - mnew); e[1] = expf(va.y - mnew);
                e[2] = expf(va.z - mnew); e[3] = expf(va.w - mnew);
                e[4] = expf(vb.x - mnew); e[5] = expf(vb.y - mnew);
                e[6] = expf(vb.z - mnew); e[7] = expf(vb.w - mnew);
                sum = ((e[0] + e[1]) + (e[2] + e[3])) + ((e[4] + e[5]) + (e[6] + e[7]));
            } else {
                #pragma unroll
                for (int i = 0; i < 8; ++i) e[i] = 0.f;
            }
            #pragma unroll
            for (int o = 1; o < 8; o <<= 1) sum += __shfl_xor(sum, o);
            bf16x8 ph, pl;   // truncation split (e >= 0)
            #pragma unroll
            for (int i = 0; i < 8; ++i) {
                unsigned u = __builtin_bit_cast(unsigned, e[i]);
                ph[i] = (short)(u >> 16);
                float r = e[i] - __builtin_bit_cast(float, u & 0xffff0000u);
                pl[i] = (short)(__builtin_bit_cast(unsigned, r) >> 16);
            }
            int poff = q * 64 + ((s ^ (q & 7)) << 3);
            *(bf16x8*)&Ph[poff] = ph;
            *(bf16x8*)&Pl[poff] = pl;
            if (s == 0 && rowok) {
                float f = expf(mold - mnew);
                lrow[q] = lrow[q] * f + sum;
                mrow[q] = mnew;
                frow[q] = f;
            }
            if (q0 == 0 && tid < 64) {
                int jj = jb + tid;
                if (jj < nTok)
                    vnrow[jj] = sqrtf(vnpart[tid][0] + vnpart[tid][1]
                                    + vnpart[tid][2] + vnpart[tid][3]);
            }
        }
        __syncthreads();
        {   // ---- PV: wave (qh, xh) computes 16q x 32d, accumulate
            float fe[4];
            #pragma unroll
            for (int e = 0; e < 4; ++e) fe[e] = frow[qh * 16 + fg * 4 + e];
            #pragma unroll
            for (int t = 0; t < 2; ++t)
                #pragma unroll
                for (int e = 0; e < 4; ++e) oacc[t][e] *= fe[e];
            #pragma unroll
            for (int s = 0; s < 2; ++s) {
                int pr = qh * 16 + fr;
                int poff = pr * 64 + (((s * 4 + fg) ^ (pr & 7)) << 3);
                bf16x8 pah = *(const bf16x8*)&Ph[poff];
                bf16x8 pal = *(const bf16x8*)&Pl[poff];
                #pragma unroll
                for (int t = 0; t < 2; ++t) {
                    int d = xh * 32 + t * 16 + fr;
                    int voff = d * 64 + (((s * 4 + fg) ^ (d & 7)) << 3);
                    bf16x8 vbh = *(const bf16x8*)&Vth[voff];
                    bf16x8 vbl = *(const bf16x8*)&Vtl[voff];
                    oacc[t] = __builtin_amdgcn_mfma_f32_16x16x32_bf16(pah, vbh, oacc[t], 0, 0, 0);
                    oacc[t] = __builtin_amdgcn_mfma_f32_16x16x32_bf16(pah, vbl, oacc[t], 0, 0, 0);
                    oacc[t] = __builtin_amdgcn_mfma_f32_16x16x32_bf16(pal, vbh, oacc[t], 0, 0, 0);
                }
            }
        }
    }
    // ---- epilogue: O = acc / l, packed store
    #pragma unroll
    for (int e = 0; e < 4; ++e) {
        int qr = qh * 16 + fg * 4 + e;
        int q = q0 + qr;
        if (q < nTok) {
            float inv = 1.0f / lrow[qr];
            #pragma unroll
            for (int t = 0; t < 2; ++t) {
                int n = h * 64 + xh * 32 + t * 16 + fr;
                outu[((size_t)b * NTOK + q) * DMODEL + n] = split_pack(oacc[t][e] * inv);
            }
        }
    }
    if (q0 == 0) {
        float m0f = mrow[0], l0 = lrow[0];
        for (int j = 1 + tid; j < nTok; j += 256)
            jacg[(size_t)bh * NPATCH + (j - 1)] = (expf(s0row[j] - m0f) / l0) * vnrow[j];
    }
}

// ------------------------------------------------------- prune decision
__global__ __launch_bounds__(256)
void decide_kernel(const float* __restrict__ jac,
                   int* __restrict__ nTokPtr, int* __restrict__ nTokNextPtr,
                   int* __restrict__ keepIdx, float* __restrict__ prevMassPtr,
                   int* __restrict__ prevValidPtr) {
    const int nTok = *nTokPtr;
    const int N = nTok - 1;
    const int tid = threadIdx.x;
    if (N <= 16) {
        if (tid == 0) { *prevValidPtr = 0; *nTokNextPtr = nTok; }
        for (int t = tid; t < nTok; t += 256) keepIdx[t] = t;
        return;
    }
    __shared__ float impF[NPATCH];
    __shared__ int   sel[NPATCH];
    __shared__ int   s_next;
    for (int j = tid; j < N; j += 256) {
        double s = 0.0;
        for (int r = 0; r < BB * NHEAD; r++) s += (double)jac[(size_t)r * NPATCH + j];
        impF[j] = (float)(s * (1.0 / 384.0));
    }
    __syncthreads();
    if (tid == 0) {
        double ms = 0.0;
        for (int j = 0; j < N; j++) ms += (double)impF[j];
        float massF = (float)ms;
        float meanF = (float)(ms / (double)N);
        double vs = 0.0;
        for (int j = 0; j < N; j++) { double d = (double)impF[j] - (double)meanF; vs += d * d; }
        float stdF = (float)sqrt(vs / (double)N);
        float rho = stdF / (meanF + 1e-6f);
        int nnext;
        if (*prevValidPtr != 0) {
            float pm = *prevMassPtr;
            float drift = fabsf(massF - pm) / (pm + 1e-6f);
            float kr = 1.0f - 0.01f * rho * (1.0f + drift);
            kr = fminf(fmaxf(kr, 0.0f), 1.0f);
            int t = (int)((double)N * (double)kr);
            nnext = t < 16 ? 16 : t;
        } else {
            nnext = N;
        }
        *prevMassPtr = massF;
        *prevValidPtr = 1;
        s_next = nnext;
        *nTokNextPtr = nnext + 1;
    }
    __syncthreads();
    int nnext = s_next;
    if (nnext < N) {
        for (int j = tid; j < N; j += 256) {
            float vj = impF[j];
            int rank = 0;
            for (int i = 0; i < N; i++) {
                float vi = impF[i];
                rank += (vi > vj || (vi == vj && i < j)) ? 1 : 0;
            }
            sel[j] = (rank < nnext) ? 1 : 0;
        }
        __syncthreads();
        if (tid == 0) {
            int c = 1;
            keepIdx[0] = 0;
            for (int j = 0; j < N; j++) if (sel[j]) keepIdx[c++] = j + 1;
        }
    } else {
        for (int t = tid; t < nTok; t += 256) keepIdx[t] = t;
    }
}

// ---------------------------------------------------------------- gather
__global__ __launch_bounds__(192)
void gather_kernel(const float* __restrict__ src, float* __restrict__ dst,
                   const int* __restrict__ keepIdx,
                   const int* __restrict__ nTokNextPtr, int* __restrict__ nTokPtr) {
    int nn = *nTokNextPtr;
    int m = blockIdx.x;
    int b = m / NTOK, t = m - b * NTOK;
    if (t < nn) {
        int s = keepIdx[t];
        const float4* sp = (const float4*)(src + ((size_t)b * NTOK + s) * DMODEL);
        float4* dp = (float4*)(dst + ((size_t)b * NTOK + t) * DMODEL);
        dp[threadIdx.x] = sp[threadIdx.x];
    }
    if (m == 0 && threadIdx.x == 0) *nTokPtr = nn;
}

// ---------------------------------------------------------------- head
__global__ __launch_bounds__(256)
void head_kernel(const float* __restrict__ lnC, const float* __restrict__ W,
                 const float* __restrict__ hb, float* __restrict__ out) {
    int b = blockIdx.x;
    int n = blockIdx.y * 256 + threadIdx.x;
    __shared__ float xs[DMODEL];
    for (int i = threadIdx.x; i < DMODEL; i += 256) xs[i] = lnC[(size_t)b * DMODEL + i];
    __syncthreads();
    if (n < NCLASS) {
        float acc = hb[n];
        for (int d = 0; d < DMODEL; d++) acc = fmaf(xs[d], W[(size_t)d * NCLASS + n], acc);
        out[(size_t)b * NCLASS + n] = acc;
    }
}

// ================================================================= launch
extern "C" void kernel_launch(void* const* d_in, const int* in_sizes, int n_in,
                              void* d_out, int out_size, void* d_ws, size_t ws_size,
                              hipStream_t stream) {
    const float* x       = (const float*)d_in[0];
    const float* patch_w = (const float*)d_in[1];
    const float* patch_b = (const float*)d_in[2];
    const float* cls_tok = (const float*)d_in[3];
    const float* pos     = (const float*)d_in[4];
    const float* ln1_w   = (const float*)d_in[5];
    const float* ln1_b   = (const float*)d_in[6];
    const float* qkv_w   = (const float*)d_in[7];
    const float* qkv_b   = (const float*)d_in[8];
    const float* proj_w  = (const float*)d_in[9];
    const float* proj_b  = (const float*)d_in[10];
    const float* ln2_w   = (const float*)d_in[11];
    const float* ln2_b   = (const float*)d_in[12];
    const float* fc1_w   = (const float*)d_in[13];
    const float* fc1_b   = (const float*)d_in[14];
    const float* fc2_w   = (const float*)d_in[15];
    const float* fc2_b   = (const float*)d_in[16];
    const float* norm_w  = (const float*)d_in[17];
    const float* norm_b  = (const float*)d_in[18];
    const float* head_w  = (const float*)d_in[19];
    const float* head_b  = (const float*)d_in[20];
    float* out = (float*)d_out;

    char* ws = (char*)d_ws;
    size_t off = 0;
    auto alloc = [&](size_t nbytes) {
        char* p = ws + off;
        off += ((nbytes + 255) / 256) * 256;
        return p;
    };
    float* tokA = (float*)alloc((size_t)MTOT * DMODEL * 4);
    float* tokB = (float*)alloc((size_t)MTOT * DMODEL * 4);
    char* uni = alloc((size_t)MTOT * 3072 * 4);   // qkvb (packed) | hbu (packed)
    unsigned* qkvb = (unsigned*)uni;
    unsigned* hbu = (unsigned*)uni;
    unsigned* xnu  = (unsigned*)alloc((size_t)MTOT * DMODEL * 4);
    unsigned* outu = (unsigned*)alloc((size_t)MTOT * DMODEL * 4);
    unsigned short* whi = (unsigned short*)alloc(WTOTAL * 2);
    unsigned short* wlo = (unsigned short*)alloc(WTOTAL * 2);
    unsigned short* wphi = (unsigned short*)alloc((size_t)768 * 768 * 2);
    unsigned short* wplo = (unsigned short*)alloc((size_t)768 * 768 * 2);
    float* jac  = (float*)alloc((size_t)BB * NHEAD * NPATCH * 4);
    float* lnC  = (float*)alloc((size_t)BB * DMODEL * 4);
    float* prevMass = (float*)alloc(32);
    int* ints = (int*)alloc(1024);
    int* nTokP = ints; int* nTokNextP = ints + 1; int* prevValidP = ints + 2;
    int* keepIdx = ints + 4;

    dim3 blk(256);
    state_init<<<dim3(1), dim3(1), 0, stream>>>(nTokP, prevValidP);
    wconv_patch<<<dim3(288), blk, 0, stream>>>(patch_w, wphi, wplo);
    cls_init<<<dim3(BB), blk, 0, stream>>>(cls_tok, pos, tokA);
    mfma_gemm<1, 3><<<dim3(49 * 6), blk, 0, stream>>>(
        x, 0, wphi, wplo, patch_b, pos, tokA, DMODEL, 768, BB * NPATCH, 49, 6, nTokP);

    float* bufs[2] = {tokA, tokB};
    const int gm = (MTOT + 127) / 128;   // 50
    for (int l = 0; l < NLAYER; l++) {
        float* cur = bufs[l & 1];
        float* nxt = bufs[(l + 1) & 1];
        wconv_layer<<<dim3(6912), blk, 0, stream>>>(
            qkv_w + (size_t)l * 768 * 2304, proj_w + (size_t)l * 768 * 768,
            fc1_w + (size_t)l * 768 * 3072, fc2_w + (size_t)l * 3072 * 768, whi, wlo);
        ln_tok<<<dim3(MTOT), blk, 0, stream>>>(cur, xnu, ln1_w + l * 768, ln1_b + l * 768, nTokP);
        mfma_gemm<0, 0><<<dim3(gm * 18), blk, 0, stream>>>(
            xnu, 768, whi + WOFF_QKV, wlo + WOFF_QKV, qkv_b + (size_t)l * 2304,
            nullptr, qkvb, 2304, 768, MTOT, gm, 18, nTokP);
        attn_v3<<<dim3(BB * NHEAD, 7), blk, 0, stream>>>(qkvb, outu, jac, nTokP);
        mfma_gemm<0, 1><<<dim3(gm * 6), blk, 0, stream>>>(
            outu, 768, whi + WOFF_PROJ, wlo + WOFF_PROJ, proj_b + (size_t)l * 768,
            cur, cur, 768, 768, MTOT, gm, 6, nTokP);
        ln_tok<<<dim3(MTOT), blk, 0, stream>>>(cur, xnu, ln2_w + l * 768, ln2_b + l * 768, nTokP);
        mfma_gemm<0, 2><<<dim3(gm * 24), blk, 0, stream>>>(
            xnu, 768, whi + WOFF_FC1, wlo + WOFF_FC1, fc1_b + (size_t)l * 3072,
            nullptr, hbu, 3072, 768, MTOT, gm, 24, nTokP);
        mfma_gemm<0, 1><<<dim3(gm * 6), blk, 0, stream>>>(
            hbu, 3072, whi + WOFF_FC2, wlo + WOFF_FC2, fc2_b + (size_t)l * 768,
            cur, cur, 768, 3072, MTOT, gm, 6, nTokP);
        decide_kernel<<<dim3(1), blk, 0, stream>>>(jac, nTokP, nTokNextP, keepIdx,
                                                   prevMass, prevValidP);
        gather_kernel<<<dim3(MTOT), dim3(192), 0, stream>>>(cur, nxt, keepIdx, nTokNextP, nTokP);
    }
    ln_cls<<<dim3(BB), blk, 0, stream>>>(bufs[0], lnC, norm_w, norm_b);
    head_kernel<<<dim3(BB, 4), blk, 0, stream>>>(lnC, head_w, head_b, out);
}